// Round 2
// baseline (562.396 us; speedup 1.0000x reference)
//
#include <hip/hip_runtime.h>
#include <cstdint>
#include <cstddef>

// PatchAttention on MI355X — round 5: attention rewrite (inline RPE table
// gather from LDS, 8-wave blocks, double-buffered K/V with async-split
// staging, 1 barrier/k-step) + split-K proj GEMM.

typedef __bf16 bf16x8 __attribute__((ext_vector_type(8)));
typedef float f32x4 __attribute__((ext_vector_type(4)));
typedef unsigned short u16x4 __attribute__((ext_vector_type(4)));

__device__ __forceinline__ unsigned short f2bf(float f) {
  unsigned u = __builtin_bit_cast(unsigned, f);
  u += 0x7fffu + ((u >> 16) & 1u);  // round-to-nearest-even
  return (unsigned short)(u >> 16);
}
__device__ __forceinline__ float bf2f(unsigned short u) {
  return __builtin_bit_cast(float, ((unsigned)u) << 16);
}

// async 16B global -> LDS (wave-uniform base + lane*16 layout)
__device__ __forceinline__ void async_ld16(const void* g, void* l) {
  __builtin_amdgcn_global_load_lds(
      (const __attribute__((address_space(1))) void*)g,
      (__attribute__((address_space(3))) void*)l, 16, 0, 0);
}

// ---------------------------------------------------------------------------
// RPE table: MLP(2 -> 512 -> 8) over the 63x63 grid -> tableT [8][4096] f32
// (transposed so the attention kernel can stage one head's column coalesced).
__global__ __launch_bounds__(256) void rpe_table_kernel(
    const float* __restrict__ w1, const float* __restrict__ b1,
    const float* __restrict__ w2, float* __restrict__ tableT) {
  int t = blockIdx.x * 256 + threadIdx.x;
  if (t >= 3969) return;
  int a = t / 63, c = t - a * 63;
  float rh = (float)(a - 31) * (1.0f / 31.0f);
  float rw = (float)(c - 31) * (1.0f / 31.0f);
  float acc[8];
#pragma unroll
  for (int h = 0; h < 8; h++) acc[h] = 0.f;
  for (int j = 0; j < 512; j++) {
    float hv = fmaxf(rh * w1[2 * j] + rw * w1[2 * j + 1] + b1[j], 0.f);
#pragma unroll
    for (int h = 0; h < 8; h++) acc[h] += hv * w2[h * 512 + j];
  }
#pragma unroll
  for (int h = 0; h < 8; h++) tableT[h * 4096 + t] = acc[h];
}

// ---------------------------------------------------------------------------
// generic fp32 -> bf16 convert, 8 elems/thread
__global__ __launch_bounds__(256) void cvt_bf16_kernel(
    const float* __restrict__ src, unsigned short* __restrict__ dst, int n8) {
  int i = blockIdx.x * 256 + threadIdx.x;
  if (i >= n8) return;
  const float4* s4 = (const float4*)src + (size_t)i * 2;
  float4 a = s4[0], b = s4[1];
  unsigned short t[8] = {f2bf(a.x), f2bf(a.y), f2bf(a.z), f2bf(a.w),
                         f2bf(b.x), f2bf(b.y), f2bf(b.z), f2bf(b.w)};
  *(uint4*)(dst + (size_t)i * 8) = *(const uint4*)t;
}

// transpose+convert: src [256][4096] f32 -> dst [4096][256] bf16
__global__ __launch_bounds__(256) void transpose_cvt_kernel(
    const float* __restrict__ src, unsigned short* __restrict__ dst) {
  __shared__ float tile[32][33];
  int bx = blockIdx.x;
  int by = blockIdx.y;
  int tx = threadIdx.x & 31, ty = threadIdx.x >> 5;
#pragma unroll
  for (int r = 0; r < 32; r += 8)
    tile[ty + r][tx] = src[(size_t)(by * 32 + ty + r) * 4096 + bx * 32 + tx];
  __syncthreads();
#pragma unroll
  for (int r = 0; r < 32; r += 8)
    dst[(size_t)(bx * 32 + ty + r) * 256 + by * 32 + tx] = f2bf(tile[tx][ty + r]);
}

// ---------------------------------------------------------------------------
// im2col: x [8,256,128,128] f32 -> A [8192, 4096=(c,p,q)] bf16
__global__ __launch_bounds__(256) void im2col_bf16_kernel(
    const float* __restrict__ x, unsigned short* __restrict__ A) {
  int gid = blockIdx.x * 256 + threadIdx.x;
  int bn = gid & 8191;
  int c = gid >> 13;
  int b = bn >> 10;
  int hw = bn & 1023;
  int h = hw >> 5, w = hw & 31;
  const float4* x4 = (const float4*)x;
  int base = ((b * 256 + c) * 128 + 4 * h) * 32 + w;
  unsigned short t[16];
#pragma unroll
  for (int p = 0; p < 4; p++) {
    float4 v = x4[base + p * 32];
    t[p * 4 + 0] = f2bf(v.x); t[p * 4 + 1] = f2bf(v.y);
    t[p * 4 + 2] = f2bf(v.z); t[p * 4 + 3] = f2bf(v.w);
  }
  unsigned short* dst = A + (size_t)bn * 4096 + c * 16;
  *(uint4*)dst = *(const uint4*)t;
  *(uint4*)(dst + 8) = *(const uint4*)(t + 8);
}

// ---------------------------------------------------------------------------
// splitk reduce: out[8192*256] bf16 = sum_{s<4} part[s][.] + bias[col]
__global__ __launch_bounds__(256) void splitk_reduce_kernel(
    const float* __restrict__ part, const float* __restrict__ bias,
    unsigned short* __restrict__ out) {
  size_t i = ((size_t)blockIdx.x * 256 + threadIdx.x) * 8;
  const float4* p = (const float4*)(part + i);
  const size_t s4 = 2097152 / 4;  // float4 stride per split
  float4 a0 = p[0], a1 = p[1];
#pragma unroll
  for (int s = 1; s < 4; s++) {
    float4 b0 = p[s * s4], b1 = p[s * s4 + 1];
    a0.x += b0.x; a0.y += b0.y; a0.z += b0.z; a0.w += b0.w;
    a1.x += b1.x; a1.y += b1.y; a1.z += b1.z; a1.w += b1.w;
  }
  int col = (int)(i & 255);
  unsigned short t8[8] = {
      f2bf(a0.x + bias[col + 0]), f2bf(a0.y + bias[col + 1]),
      f2bf(a0.z + bias[col + 2]), f2bf(a0.w + bias[col + 3]),
      f2bf(a1.x + bias[col + 4]), f2bf(a1.y + bias[col + 5]),
      f2bf(a1.z + bias[col + 6]), f2bf(a1.w + bias[col + 7])};
  *(uint4*)(out + i) = *(const uint4*)t8;
}

// ---------------------------------------------------------------------------
// bf16 MFMA GEMM: C[M,N] = A[M,K] * B^T (B given [N,K] bf16) + bias.
// CMODE: 1 = bf16 C, 2 = fused col2im into y[8,256,128,128] f32,
//        3 = fused QKV split: Q,K -> [bh][n][32] bf16 (Q scaled), V -> V^T
//            [bh][32][1024] bf16; Cv points at the 3-section base.
//        4 = split-K: blockIdx.z selects a K-slice of length K (lda spans the
//            full row); f32 partials at Cv + z*M*N, no bias.
// k-loop double-buffered: stage(t+1) overlaps ds_read+MFMA(t).
template <int CMODE>
__global__ __launch_bounds__(256) void gemm_mfma_kernel(
    const unsigned short* __restrict__ A, const unsigned short* __restrict__ B,
    const float* __restrict__ bias, void* __restrict__ Cv,
    int M, int N, int K, int lda, int ldb, int ldc) {
  __shared__ unsigned short As[2 * 128 * 32];
  __shared__ unsigned short Bs[2 * 128 * 32];
  int tid = threadIdx.x;
  int lane = tid & 63;
  int wave = tid >> 6;
  int m0 = blockIdx.y * 128, n0 = blockIdx.x * 128;
  int wm = (wave & 1) * 64, wn = (wave >> 1) * 64;

  if (CMODE == 4) {
    int s = blockIdx.z;
    A += (size_t)s * K;  // K = slice length; lda = full row stride
    B += (size_t)s * K;
    Cv = (void*)((float*)Cv + (size_t)s * M * N);
  }

  f32x4 acc[4][4];
#pragma unroll
  for (int i = 0; i < 4; i++)
#pragma unroll
    for (int j = 0; j < 4; j++) acc[i][j] = (f32x4){0.f, 0.f, 0.f, 0.f};

  int f0 = tid, f1 = tid + 256;
  const unsigned short* Ag0 = A + (size_t)(m0 + (f0 >> 2)) * lda + (f0 & 3) * 8;
  const unsigned short* Ag1 = A + (size_t)(m0 + (f1 >> 2)) * lda + (f1 & 3) * 8;
  const unsigned short* Bg0 = B + (size_t)(n0 + (f0 >> 2)) * ldb + (f0 & 3) * 8;
  const unsigned short* Bg1 = B + (size_t)(n0 + (f1 >> 2)) * ldb + (f1 & 3) * 8;
  unsigned short* Al0 = As + f0 * 8;
  unsigned short* Al1 = As + f1 * 8;
  unsigned short* Bl0 = Bs + f0 * 8;
  unsigned short* Bl1 = Bs + f1 * 8;

  int fr = lane & 15;
  int fh = lane >> 4;

  int ntiles = K >> 5;
  // prologue: stage tile 0 into buffer 0
  async_ld16(Ag0, Al0);
  async_ld16(Ag1, Al1);
  async_ld16(Bg0, Bl0);
  async_ld16(Bg1, Bl1);
  __syncthreads();

  for (int t = 0; t < ntiles; t++) {
    int cur = (t & 1) << 12;  // 0 / 4096 elements
    int nxt = cur ^ 4096;
    if (t + 1 < ntiles) {  // stage next tile while computing this one
      int kn = (t + 1) << 5;
      async_ld16(Ag0 + kn, Al0 + nxt);
      async_ld16(Ag1 + kn, Al1 + nxt);
      async_ld16(Bg0 + kn, Bl0 + nxt);
      async_ld16(Bg1 + kn, Bl1 + nxt);
    }
    const unsigned short* Asc = As + cur;
    const unsigned short* Bsc = Bs + cur;
    bf16x8 af[4], bfr[4];
#pragma unroll
    for (int tt = 0; tt < 4; tt++) {
      af[tt] = *(const bf16x8*)(Asc + (wm + tt * 16 + fr) * 32 + fh * 8);
      bfr[tt] = *(const bf16x8*)(Bsc + (wn + tt * 16 + fr) * 32 + fh * 8);
    }
#pragma unroll
    for (int mt = 0; mt < 4; mt++)
#pragma unroll
      for (int nt = 0; nt < 4; nt++)
        acc[mt][nt] = __builtin_amdgcn_mfma_f32_16x16x32_bf16(
            af[mt], bfr[nt], acc[mt][nt], 0, 0, 0);
    __syncthreads();  // drains next-tile vmcnt; frees buffer cur for t+2
  }

  // epilogue: C/D layout col = lane&15, row = (lane>>4)*4 + reg
#pragma unroll
  for (int mt = 0; mt < 4; mt++) {
    int row0 = m0 + wm + mt * 16 + fh * 4;
    if (CMODE == 2) {
      int b = row0 >> 10, hp = (row0 >> 5) & 31, wp = row0 & 31;
      size_t rowoff0 = (size_t)b * 4194304 + hp * 512 + wp * 4;
      float* y = (float*)Cv;
#pragma unroll
      for (int nt = 0; nt < 4; nt++) {
        int col = n0 + wn + nt * 16 + fr;
        int o = col >> 4, p = (col >> 2) & 3, q = col & 3;
        size_t coloff = (size_t)o * 16384 + p * 128 + q;
        float bv = bias[o];
#pragma unroll
        for (int r = 0; r < 4; r++)
          y[rowoff0 + r * 4 + coloff] = acc[mt][nt][r] + bv;
      }
    } else if (CMODE == 3) {
      unsigned short* base = (unsigned short*)Cv;
#pragma unroll
      for (int nt = 0; nt < 4; nt++) {
        int col = n0 + wn + nt * 16 + fr;
        int which = col >> 8, hh = (col >> 5) & 7, d = col & 31;
        float bv = bias[col];
#pragma unroll
        for (int r = 0; r < 4; r++) {
          int row = row0 + r;
          int bb = row >> 10, nn = row & 1023;
          int bh = bb * 8 + hh;
          float v = acc[mt][nt][r] + bv;
          if (which == 0) v *= 0.17677669529663687f;  // 1/sqrt(32)
          size_t addr;
          if (which < 2)
            addr = (size_t)which * 2097152 + ((size_t)bh * 1024 + nn) * 32 + d;
          else
            addr = (size_t)2 * 2097152 + (size_t)bh * 32768 + (size_t)d * 1024 + nn;
          base[addr] = f2bf(v);
        }
      }
    } else if (CMODE == 4) {
      float* Cp = (float*)Cv;
#pragma unroll
      for (int nt = 0; nt < 4; nt++) {
        int col = n0 + wn + nt * 16 + fr;
#pragma unroll
        for (int r = 0; r < 4; r++)
          Cp[(size_t)(row0 + r) * ldc + col] = acc[mt][nt][r];
      }
    } else {
#pragma unroll
      for (int nt = 0; nt < 4; nt++) {
        int col = n0 + wn + nt * 16 + fr;
        float bv = bias ? bias[col] : 0.f;
        unsigned short* C = (unsigned short*)Cv;
#pragma unroll
        for (int r = 0; r < 4; r++)
          C[(size_t)(row0 + r) * ldc + col] = f2bf(acc[mt][nt][r] + bv);
      }
    }
  }
}

// ---------------------------------------------------------------------------
// MFMA flash attention, round 5.
// Block = (h, b, 128-q tile), 512 threads = 8 waves, 16 q per wave.
// - RPE bias gathered inline from the per-head table column staged in LDS
//   (idx arithmetic gives 4 CONSECUTIVE table entries per (mt,g) group).
// - K/V tiles double-buffered; global loads for tile t+2 issued at end of
//   body t (reg-staged), LDS-written at end of body t+1 -> one full compute
//   phase of latency hiding; ONE __syncthreads per k-step.
// - S^T = K·Q^T; C-layout: q = lane&15, k = mt*16 + (lane>>4)*4 + r.
__global__ __launch_bounds__(512) void attn_mfma_kernel(
    const unsigned short* __restrict__ Qb, const unsigned short* __restrict__ Kb,
    const unsigned short* __restrict__ Vtb,
    const float* __restrict__ tableT,
    unsigned short* __restrict__ out) {
  __shared__ float smf[12804];  // 51216 B
  float* th = smf;                                     // [3969] table col
  unsigned short* Ks = (unsigned short*)(smf + 3972);  // 2 x [64][36]
  unsigned short* Vt = (unsigned short*)(smf + 6276);  // 2 x [32][68]
  unsigned short* Ps = (unsigned short*)(smf + 8452);  // 8 x [16][68]
  unsigned short* Qs = (unsigned short*)(smf + 8452);  // [128][36] alias (Q read once)

  int tid = threadIdx.x;
  int lane = tid & 63, w = tid >> 6;
  int n = lane & 15, g = lane >> 4;
  int blk = blockIdx.x;
  int qt = blk & 7, b = (blk >> 3) & 7, h = blk >> 6;
  int bh = b * 8 + h;
  int q0 = qt * 128;

  const unsigned short* Qg = Qb + ((size_t)bh * 1024 + q0) * 32;
  const unsigned short* Kg = Kb + (size_t)bh * 1024 * 32;
  const unsigned short* Vg = Vtb + (size_t)bh * 32 * 1024;
  const float* tg = tableT + (size_t)h * 4096;

  // stage Q [128][32] -> Qs [128][36] (one uint4 per thread)
  {
    int r = tid >> 2, c = tid & 3;
    *(uint4*)(Qs + r * 36 + c * 8) = *(const uint4*)(Qg + (size_t)r * 32 + c * 8);
  }
  // stage per-head table column (coalesced)
  for (int i = tid; i < 3969; i += 512) th[i] = tg[i];

  // staging duty: waves 0-3 -> K tile (64x32, 256 chunks),
  //               waves 4-7 -> V^T tile (32x64, 256 chunks)
  bool isK = tid < 256;
  int cidx = isK ? tid : tid - 256;
  const unsigned short* gsrc = isK
      ? (Kg + (size_t)(cidx >> 2) * 32 + (cidx & 3) * 8)
      : (Vg + (size_t)(cidx >> 3) * 1024 + (cidx & 7) * 8);
  int gstep = isK ? 2048 : 64;  // elems per 64-k tile
  unsigned short* lbase = isK ? Ks : Vt;
  int loff = isK ? ((cidx >> 2) * 36 + (cidx & 3) * 8)
                 : ((cidx >> 3) * 68 + (cidx & 7) * 8);
  int lbufstep = isK ? 2304 : 2176;  // elems per buffer

  uint4 greg = *(const uint4*)(gsrc);  // tile 0
  __syncthreads();                     // Q + table staged

  bf16x8 qf = *(const bf16x8*)(Qs + (w * 16 + n) * 36 + g * 8);

  *(uint4*)(lbase + loff) = greg;           // write buf0 (vmcnt auto-wait)
  greg = *(const uint4*)(gsrc + gstep);     // tile 1 in flight
  __syncthreads();  // buf0 visible; qf reads done before Ps overwrites

  f32x4 oacc[2];
#pragma unroll
  for (int i = 0; i < 2; i++) oacc[i] = (f32x4){0.f, 0.f, 0.f, 0.f};
  float m_run = -1e30f, l_run = 0.f;

  unsigned short* Pw = Ps + w * 1088;  // [16][68] per wave
  int q = q0 + w * 16 + n;
  int qh = q >> 5, qw = q & 31;

  for (int t = 0; t < 16; t++) {
    const unsigned short* Kc = Ks + (t & 1) * 2304;
    const unsigned short* Vc = Vt + (t & 1) * 2176;
    int k0 = t * 64;

    // S^T[k][q] = K·Q^T
    f32x4 s[4];
    __builtin_amdgcn_s_setprio(1);
#pragma unroll
    for (int mt = 0; mt < 4; mt++) {
      bf16x8 kf = *(const bf16x8*)(Kc + (mt * 16 + n) * 36 + g * 8);
      s[mt] = __builtin_amdgcn_mfma_f32_16x16x32_bf16(
          kf, qf, (f32x4){0.f, 0.f, 0.f, 0.f}, 0, 0, 0);
    }
    __builtin_amdgcn_s_setprio(0);

    // + RPE bias from LDS table: k = k0 + mt*16 + g*4 + r,
    // idx(r) = (qh-kh+31)*63 + (qw-kw0+31) - r  (4 consecutive entries)
#pragma unroll
    for (int mt = 0; mt < 4; mt++) {
      int kb = k0 + mt * 16 + g * 4;
      int ib = (qh - (kb >> 5) + 31) * 63 + (qw - (kb & 31) + 31);
      s[mt][0] += th[ib];
      s[mt][1] += th[ib - 1];
      s[mt][2] += th[ib - 2];
      s[mt][3] += th[ib - 3];
    }

    // online softmax for this lane's q (reduce regs, then g-groups via xor)
    float mx = -1e30f;
#pragma unroll
    for (int mt = 0; mt < 4; mt++)
#pragma unroll
      for (int r = 0; r < 4; r++) mx = fmaxf(mx, s[mt][r]);
    mx = fmaxf(mx, __shfl_xor(mx, 16, 64));
    mx = fmaxf(mx, __shfl_xor(mx, 32, 64));
    float m_new = fmaxf(m_run, mx);
    float alpha = __expf(m_run - m_new);
    m_run = m_new;
    float ls = 0.f;
#pragma unroll
    for (int mt = 0; mt < 4; mt++) {
#pragma unroll
      for (int r = 0; r < 4; r++) {
        float p = __expf(s[mt][r] - m_new);
        s[mt][r] = p;
        ls += p;
      }
      u16x4 pk = {f2bf(s[mt][0]), f2bf(s[mt][1]), f2bf(s[mt][2]),
                  f2bf(s[mt][3])};
      *(u16x4*)(Pw + n * 68 + mt * 16 + g * 4) = pk;
    }
    ls += __shfl_xor(ls, 16, 64);
    ls += __shfl_xor(ls, 32, 64);
    l_run = l_run * alpha + ls;

    // O^T += V^T · P^T  (same-wave LDS RAW on Pw: compiler inserts lgkmcnt)
#pragma unroll
    for (int dt = 0; dt < 2; dt++)
#pragma unroll
      for (int r = 0; r < 4; r++) oacc[dt][r] *= alpha;
    __builtin_amdgcn_s_setprio(1);
#pragma unroll
    for (int kt = 0; kt < 2; kt++) {
      bf16x8 vf0 = *(const bf16x8*)(Vc + n * 68 + kt * 32 + g * 8);
      bf16x8 vf1 = *(const bf16x8*)(Vc + (16 + n) * 68 + kt * 32 + g * 8);
      bf16x8 pf = *(const bf16x8*)(Pw + n * 68 + kt * 32 + g * 8);
      oacc[0] = __builtin_amdgcn_mfma_f32_16x16x32_bf16(vf0, pf, oacc[0], 0, 0, 0);
      oacc[1] = __builtin_amdgcn_mfma_f32_16x16x32_bf16(vf1, pf, oacc[1], 0, 0, 0);
    }
    __builtin_amdgcn_s_setprio(0);

    // stage: LDS-write tile t+1 (loaded one phase ago), issue load tile t+2
    if (t < 15) {
      *(uint4*)(lbase + ((t + 1) & 1) * lbufstep + loff) = greg;
      if (t < 14) greg = *(const uint4*)(gsrc + (size_t)(t + 2) * gstep);
    }
    __syncthreads();
  }

  // epilogue: O^T C-layout -> out[token][256] bf16
  float invl = 1.f / l_run;
  unsigned short* ob = out + ((size_t)(b * 1024 + q) * 256) + h * 32;
#pragma unroll
  for (int dt = 0; dt < 2; dt++) {
    u16x4 o4 = {f2bf(oacc[dt][0] * invl), f2bf(oacc[dt][1] * invl),
                f2bf(oacc[dt][2] * invl), f2bf(oacc[dt][3] * invl)};
    *(u16x4*)(ob + dt * 16 + g * 4) = o4;
  }
}

// ---------------------------------------------------------------------------
extern "C" void kernel_launch(void* const* d_in, const int* in_sizes, int n_in,
                              void* d_out, int out_size, void* d_ws, size_t ws_size,
                              hipStream_t stream) {
  const float* x         = (const float*)d_in[0];
  const float* w_embed   = (const float*)d_in[1];
  const float* b_embed   = (const float*)d_in[2];
  const float* cpb_w1    = (const float*)d_in[3];
  const float* cpb_b1    = (const float*)d_in[4];
  const float* cpb_w2    = (const float*)d_in[5];
  const float* w_qkv     = (const float*)d_in[6];
  const float* b_qkv     = (const float*)d_in[7];
  const float* w_proj    = (const float*)d_in[8];
  const float* b_proj    = (const float*)d_in[9];
  const float* w_unembed = (const float*)d_in[10];
  const float* b_unembed = (const float*)d_in[11];
  float* out = (float*)d_out;

  // workspace layout (~105 MB)
  char* w = (char*)d_ws;
  unsigned short* Abig  = (unsigned short*)w; w += (size_t)8192 * 4096 * 2;  // 64 MB
  unsigned short* tok   = (unsigned short*)w; w += (size_t)8192 * 256 * 2;   //  4 MB
  unsigned short* wE    = (unsigned short*)w; w += (size_t)1048576 * 2;      //  2 MB
  unsigned short* wQ    = (unsigned short*)w; w += (size_t)196608 * 2;       // 384 KB
  unsigned short* wP    = (unsigned short*)w; w += (size_t)65536 * 2;        // 128 KB
  unsigned short* wUt   = (unsigned short*)w; w += (size_t)1048576 * 2;      //  2 MB
  float*          tableT= (float*)w;          w += (size_t)32768 * 4;        // 128 KB
  float*          PART  = (float*)w;          w += (size_t)8388608 * 4;      // 32 MB

  // live-range aliases inside PART (partials dead once reduced):
  unsigned short* qkvB  = (unsigned short*)PART;                     // 12 MB
  unsigned short* attno = (unsigned short*)((char*)PART + 12582912); //  4 MB
  unsigned short* z2    = (unsigned short*)((char*)PART + 16777216); //  4 MB
  unsigned short* Qb  = qkvB;
  unsigned short* Kb  = qkvB + 2097152;
  unsigned short* Vtb = qkvB + 2 * 2097152;

  // ---- prep (weights, im2col, RPE table) ----
  cvt_bf16_kernel<<<512, 256, 0, stream>>>(w_embed, wE, 131072);
  cvt_bf16_kernel<<<96, 256, 0, stream>>>(w_qkv, wQ, 24576);
  cvt_bf16_kernel<<<32, 256, 0, stream>>>(w_proj, wP, 8192);
  transpose_cvt_kernel<<<dim3(128, 8), 256, 0, stream>>>(w_unembed, wUt);
  im2col_bf16_kernel<<<8192, 256, 0, stream>>>(x, Abig);
  rpe_table_kernel<<<16, 256, 0, stream>>>(cpb_w1, cpb_b1, cpb_w2, tableT);

  // ---- embed: split-K x4 -> f32 partials (PART) -> reduce(+bias) -> tok ----
  gemm_mfma_kernel<4><<<dim3(2, 64, 4), 256, 0, stream>>>(
      Abig, wE, nullptr, PART, 8192, 256, 1024, 4096, 4096, 256);
  splitk_reduce_kernel<<<1024, 256, 0, stream>>>(PART, b_embed, tok);

  // ---- qkv + fused split/scale/transpose into Qb/Kb/Vtb ----
  gemm_mfma_kernel<3><<<dim3(6, 64), 256, 0, stream>>>(
      tok, wQ, b_qkv, qkvB, 8192, 768, 256, 256, 256, 0);

  // ---- attention (inline RPE gather) ----
  attn_mfma_kernel<<<512, 512, 0, stream>>>(Qb, Kb, Vtb, tableT, attno);

  // ---- proj: split-K x4 (partials in dead Abig) -> reduce -> z2 ----
  gemm_mfma_kernel<4><<<dim3(2, 64, 4), 256, 0, stream>>>(
      attno, wP, nullptr, (float*)Abig, 8192, 256, 64, 256, 256, 256);
  splitk_reduce_kernel<<<1024, 256, 0, stream>>>((float*)Abig, b_proj, z2);

  // ---- unembed + fused col2im ----
  gemm_mfma_kernel<2><<<dim3(32, 64), 256, 0, stream>>>(
      z2, wUt, b_unembed, out, 8192, 4096, 256, 256, 256, 0);
}

// Round 3
// 547.355 us; speedup vs baseline: 1.0275x; 1.0275x over previous
//
#include <hip/hip_runtime.h>
#include <cstdint>
#include <cstddef>

// PatchAttention on MI355X — round 6: barrier-free flash attention.
// K/V MFMA fragments loaded directly global->reg (L2-resident), LDS only for
// RPE table + per-wave double-buffered P scratch; waves free-run (no lockstep,
// no vmcnt drain). Same-XCD mapping for all q-tiles of one (b,h).

typedef __bf16 bf16x8 __attribute__((ext_vector_type(8)));
typedef float f32x4 __attribute__((ext_vector_type(4)));
typedef unsigned short u16x4 __attribute__((ext_vector_type(4)));

__device__ __forceinline__ unsigned short f2bf(float f) {
  unsigned u = __builtin_bit_cast(unsigned, f);
  u += 0x7fffu + ((u >> 16) & 1u);  // round-to-nearest-even
  return (unsigned short)(u >> 16);
}
__device__ __forceinline__ float bf2f(unsigned short u) {
  return __builtin_bit_cast(float, ((unsigned)u) << 16);
}

// async 16B global -> LDS (wave-uniform base + lane*16 layout)
__device__ __forceinline__ void async_ld16(const void* g, void* l) {
  __builtin_amdgcn_global_load_lds(
      (const __attribute__((address_space(1))) void*)g,
      (__attribute__((address_space(3))) void*)l, 16, 0, 0);
}

// ---------------------------------------------------------------------------
// RPE table: MLP(2 -> 512 -> 8) over the 63x63 grid -> tableT [8][4096] f32
// (transposed so the attention kernel can stage one head's column coalesced).
__global__ __launch_bounds__(256) void rpe_table_kernel(
    const float* __restrict__ w1, const float* __restrict__ b1,
    const float* __restrict__ w2, float* __restrict__ tableT) {
  int t = blockIdx.x * 256 + threadIdx.x;
  if (t >= 3969) return;
  int a = t / 63, c = t - a * 63;
  float rh = (float)(a - 31) * (1.0f / 31.0f);
  float rw = (float)(c - 31) * (1.0f / 31.0f);
  float acc[8];
#pragma unroll
  for (int h = 0; h < 8; h++) acc[h] = 0.f;
  for (int j = 0; j < 512; j++) {
    float hv = fmaxf(rh * w1[2 * j] + rw * w1[2 * j + 1] + b1[j], 0.f);
#pragma unroll
    for (int h = 0; h < 8; h++) acc[h] += hv * w2[h * 512 + j];
  }
#pragma unroll
  for (int h = 0; h < 8; h++) tableT[h * 4096 + t] = acc[h];
}

// ---------------------------------------------------------------------------
// generic fp32 -> bf16 convert, 8 elems/thread
__global__ __launch_bounds__(256) void cvt_bf16_kernel(
    const float* __restrict__ src, unsigned short* __restrict__ dst, int n8) {
  int i = blockIdx.x * 256 + threadIdx.x;
  if (i >= n8) return;
  const float4* s4 = (const float4*)src + (size_t)i * 2;
  float4 a = s4[0], b = s4[1];
  unsigned short t[8] = {f2bf(a.x), f2bf(a.y), f2bf(a.z), f2bf(a.w),
                         f2bf(b.x), f2bf(b.y), f2bf(b.z), f2bf(b.w)};
  *(uint4*)(dst + (size_t)i * 8) = *(const uint4*)t;
}

// transpose+convert: src [256][4096] f32 -> dst [4096][256] bf16
__global__ __launch_bounds__(256) void transpose_cvt_kernel(
    const float* __restrict__ src, unsigned short* __restrict__ dst) {
  __shared__ float tile[32][33];
  int bx = blockIdx.x;
  int by = blockIdx.y;
  int tx = threadIdx.x & 31, ty = threadIdx.x >> 5;
#pragma unroll
  for (int r = 0; r < 32; r += 8)
    tile[ty + r][tx] = src[(size_t)(by * 32 + ty + r) * 4096 + bx * 32 + tx];
  __syncthreads();
#pragma unroll
  for (int r = 0; r < 32; r += 8)
    dst[(size_t)(bx * 32 + ty + r) * 256 + by * 32 + tx] = f2bf(tile[tx][ty + r]);
}

// ---------------------------------------------------------------------------
// im2col: x [8,256,128,128] f32 -> A [8192, 4096=(c,p,q)] bf16
__global__ __launch_bounds__(256) void im2col_bf16_kernel(
    const float* __restrict__ x, unsigned short* __restrict__ A) {
  int gid = blockIdx.x * 256 + threadIdx.x;
  int bn = gid & 8191;
  int c = gid >> 13;
  int b = bn >> 10;
  int hw = bn & 1023;
  int h = hw >> 5, w = hw & 31;
  const float4* x4 = (const float4*)x;
  int base = ((b * 256 + c) * 128 + 4 * h) * 32 + w;
  unsigned short t[16];
#pragma unroll
  for (int p = 0; p < 4; p++) {
    float4 v = x4[base + p * 32];
    t[p * 4 + 0] = f2bf(v.x); t[p * 4 + 1] = f2bf(v.y);
    t[p * 4 + 2] = f2bf(v.z); t[p * 4 + 3] = f2bf(v.w);
  }
  unsigned short* dst = A + (size_t)bn * 4096 + c * 16;
  *(uint4*)dst = *(const uint4*)t;
  *(uint4*)(dst + 8) = *(const uint4*)(t + 8);
}

// ---------------------------------------------------------------------------
// splitk reduce: out[8192*256] bf16 = sum_{s<4} part[s][.] + bias[col]
__global__ __launch_bounds__(256) void splitk_reduce_kernel(
    const float* __restrict__ part, const float* __restrict__ bias,
    unsigned short* __restrict__ out) {
  size_t i = ((size_t)blockIdx.x * 256 + threadIdx.x) * 8;
  const float4* p = (const float4*)(part + i);
  const size_t s4 = 2097152 / 4;  // float4 stride per split
  float4 a0 = p[0], a1 = p[1];
#pragma unroll
  for (int s = 1; s < 4; s++) {
    float4 b0 = p[s * s4], b1 = p[s * s4 + 1];
    a0.x += b0.x; a0.y += b0.y; a0.z += b0.z; a0.w += b0.w;
    a1.x += b1.x; a1.y += b1.y; a1.z += b1.z; a1.w += b1.w;
  }
  int col = (int)(i & 255);
  unsigned short t8[8] = {
      f2bf(a0.x + bias[col + 0]), f2bf(a0.y + bias[col + 1]),
      f2bf(a0.z + bias[col + 2]), f2bf(a0.w + bias[col + 3]),
      f2bf(a1.x + bias[col + 4]), f2bf(a1.y + bias[col + 5]),
      f2bf(a1.z + bias[col + 6]), f2bf(a1.w + bias[col + 7])};
  *(uint4*)(out + i) = *(const uint4*)t8;
}

// ---------------------------------------------------------------------------
// bf16 MFMA GEMM: C[M,N] = A[M,K] * B^T (B given [N,K] bf16) + bias.
// CMODE: 1 = bf16 C, 2 = fused col2im into y[8,256,128,128] f32,
//        3 = fused QKV split: Q,K -> [bh][n][32] bf16 (Q scaled), V -> V^T
//            [bh][32][1024] bf16; Cv points at the 3-section base.
//        4 = split-K: blockIdx.z selects a K-slice of length K (lda spans the
//            full row); f32 partials at Cv + z*M*N, no bias.
// k-loop double-buffered: stage(t+1) overlaps ds_read+MFMA(t).
template <int CMODE>
__global__ __launch_bounds__(256) void gemm_mfma_kernel(
    const unsigned short* __restrict__ A, const unsigned short* __restrict__ B,
    const float* __restrict__ bias, void* __restrict__ Cv,
    int M, int N, int K, int lda, int ldb, int ldc) {
  __shared__ unsigned short As[2 * 128 * 32];
  __shared__ unsigned short Bs[2 * 128 * 32];
  int tid = threadIdx.x;
  int lane = tid & 63;
  int wave = tid >> 6;
  int m0 = blockIdx.y * 128, n0 = blockIdx.x * 128;
  int wm = (wave & 1) * 64, wn = (wave >> 1) * 64;

  if (CMODE == 4) {
    int s = blockIdx.z;
    A += (size_t)s * K;  // K = slice length; lda = full row stride
    B += (size_t)s * K;
    Cv = (void*)((float*)Cv + (size_t)s * M * N);
  }

  f32x4 acc[4][4];
#pragma unroll
  for (int i = 0; i < 4; i++)
#pragma unroll
    for (int j = 0; j < 4; j++) acc[i][j] = (f32x4){0.f, 0.f, 0.f, 0.f};

  int f0 = tid, f1 = tid + 256;
  const unsigned short* Ag0 = A + (size_t)(m0 + (f0 >> 2)) * lda + (f0 & 3) * 8;
  const unsigned short* Ag1 = A + (size_t)(m0 + (f1 >> 2)) * lda + (f1 & 3) * 8;
  const unsigned short* Bg0 = B + (size_t)(n0 + (f0 >> 2)) * ldb + (f0 & 3) * 8;
  const unsigned short* Bg1 = B + (size_t)(n0 + (f1 >> 2)) * ldb + (f1 & 3) * 8;
  unsigned short* Al0 = As + f0 * 8;
  unsigned short* Al1 = As + f1 * 8;
  unsigned short* Bl0 = Bs + f0 * 8;
  unsigned short* Bl1 = Bs + f1 * 8;

  int fr = lane & 15;
  int fh = lane >> 4;

  int ntiles = K >> 5;
  // prologue: stage tile 0 into buffer 0
  async_ld16(Ag0, Al0);
  async_ld16(Ag1, Al1);
  async_ld16(Bg0, Bl0);
  async_ld16(Bg1, Bl1);
  __syncthreads();

  for (int t = 0; t < ntiles; t++) {
    int cur = (t & 1) << 12;  // 0 / 4096 elements
    int nxt = cur ^ 4096;
    if (t + 1 < ntiles) {  // stage next tile while computing this one
      int kn = (t + 1) << 5;
      async_ld16(Ag0 + kn, Al0 + nxt);
      async_ld16(Ag1 + kn, Al1 + nxt);
      async_ld16(Bg0 + kn, Bl0 + nxt);
      async_ld16(Bg1 + kn, Bl1 + nxt);
    }
    const unsigned short* Asc = As + cur;
    const unsigned short* Bsc = Bs + cur;
    bf16x8 af[4], bfr[4];
#pragma unroll
    for (int tt = 0; tt < 4; tt++) {
      af[tt] = *(const bf16x8*)(Asc + (wm + tt * 16 + fr) * 32 + fh * 8);
      bfr[tt] = *(const bf16x8*)(Bsc + (wn + tt * 16 + fr) * 32 + fh * 8);
    }
#pragma unroll
    for (int mt = 0; mt < 4; mt++)
#pragma unroll
      for (int nt = 0; nt < 4; nt++)
        acc[mt][nt] = __builtin_amdgcn_mfma_f32_16x16x32_bf16(
            af[mt], bfr[nt], acc[mt][nt], 0, 0, 0);
    __syncthreads();  // drains next-tile vmcnt; frees buffer cur for t+2
  }

  // epilogue: C/D layout col = lane&15, row = (lane>>4)*4 + reg
#pragma unroll
  for (int mt = 0; mt < 4; mt++) {
    int row0 = m0 + wm + mt * 16 + fh * 4;
    if (CMODE == 2) {
      int b = row0 >> 10, hp = (row0 >> 5) & 31, wp = row0 & 31;
      size_t rowoff0 = (size_t)b * 4194304 + hp * 512 + wp * 4;
      float* y = (float*)Cv;
#pragma unroll
      for (int nt = 0; nt < 4; nt++) {
        int col = n0 + wn + nt * 16 + fr;
        int o = col >> 4, p = (col >> 2) & 3, q = col & 3;
        size_t coloff = (size_t)o * 16384 + p * 128 + q;
        float bv = bias[o];
#pragma unroll
        for (int r = 0; r < 4; r++)
          y[rowoff0 + r * 4 + coloff] = acc[mt][nt][r] + bv;
      }
    } else if (CMODE == 3) {
      unsigned short* base = (unsigned short*)Cv;
#pragma unroll
      for (int nt = 0; nt < 4; nt++) {
        int col = n0 + wn + nt * 16 + fr;
        int which = col >> 8, hh = (col >> 5) & 7, d = col & 31;
        float bv = bias[col];
#pragma unroll
        for (int r = 0; r < 4; r++) {
          int row = row0 + r;
          int bb = row >> 10, nn = row & 1023;
          int bh = bb * 8 + hh;
          float v = acc[mt][nt][r] + bv;
          if (which == 0) v *= 0.17677669529663687f;  // 1/sqrt(32)
          size_t addr;
          if (which < 2)
            addr = (size_t)which * 2097152 + ((size_t)bh * 1024 + nn) * 32 + d;
          else
            addr = (size_t)2 * 2097152 + (size_t)bh * 32768 + (size_t)d * 1024 + nn;
          base[addr] = f2bf(v);
        }
      }
    } else if (CMODE == 4) {
      float* Cp = (float*)Cv;
#pragma unroll
      for (int nt = 0; nt < 4; nt++) {
        int col = n0 + wn + nt * 16 + fr;
#pragma unroll
        for (int r = 0; r < 4; r++)
          Cp[(size_t)(row0 + r) * ldc + col] = acc[mt][nt][r];
      }
    } else {
#pragma unroll
      for (int nt = 0; nt < 4; nt++) {
        int col = n0 + wn + nt * 16 + fr;
        float bv = bias ? bias[col] : 0.f;
        unsigned short* C = (unsigned short*)Cv;
#pragma unroll
        for (int r = 0; r < 4; r++)
          C[(size_t)(row0 + r) * ldc + col] = f2bf(acc[mt][nt][r] + bv);
      }
    }
  }
}

// ---------------------------------------------------------------------------
// MFMA flash attention, round 6 — BARRIER-FREE main loop.
// Block = 512 threads = 8 independent waves, 16 q-rows each.
// K/V fragments come straight from global (L2-resident; each (b,h)'s 8
// q-tile blocks map to ONE XCD via h = blk&7). LDS: RPE table (read-only
// after one prologue barrier) + per-wave double-buffered P scratch (same-wave
// lgkmcnt ordering only). kf double-buffered global->reg prefetch; vf loads
// issued at step top, consumed after softmax.
__global__ __launch_bounds__(512) void attn_mfma_kernel(
    const unsigned short* __restrict__ Qb, const unsigned short* __restrict__ Kb,
    const unsigned short* __restrict__ Vtb,
    const float* __restrict__ tableT,
    unsigned short* __restrict__ out) {
  __shared__ float th[3972];                 // per-head RPE table column
  __shared__ unsigned short Ps[2][8][1088];  // [buf][wave][16*68] P scratch

  int tid = threadIdx.x;
  int lane = tid & 63, w = tid >> 6;
  int n = lane & 15, g = lane >> 4;
  int blk = blockIdx.x;
  // h = blk&7 so the 8 q-tiles of one (b,h) land on one XCD (K/V L2 reuse)
  int h = blk & 7, b = (blk >> 3) & 7, qt = blk >> 6;
  int bh = b * 8 + h;
  int q0 = qt * 128;

  const unsigned short* Qg = Qb + ((size_t)bh * 1024 + q0) * 32;
  const unsigned short* Kg = Kb + (size_t)bh * 1024 * 32;
  const unsigned short* Vg = Vtb + (size_t)bh * 32 * 1024;
  const float* tg = tableT + (size_t)h * 4096;

  // stage per-head table column (only LDS data shared across waves)
  for (int i = tid; i < 3969; i += 512) th[i] = tg[i];

  // Q fragment direct from global (read once)
  bf16x8 qf = *(const bf16x8*)(Qg + (size_t)(w * 16 + n) * 32 + g * 8);

  __syncthreads();  // table ready — the ONLY barrier

  f32x4 oacc[2];
  oacc[0] = (f32x4){0.f, 0.f, 0.f, 0.f};
  oacc[1] = (f32x4){0.f, 0.f, 0.f, 0.f};
  float m_run = -1e30f, l_run = 0.f;  // l_run is g-partial (reduced at end)

  int q = q0 + w * 16 + n;
  int tbase = (q >> 5) * 63 + (q & 31);  // qh*63 + qw

  unsigned short* Pw0 = &Ps[0][w][0];
  unsigned short* Pw1 = &Ps[1][w][0];

  bf16x8 kf[2][4], vf[4];
#pragma unroll
  for (int mt = 0; mt < 4; mt++)  // K frags for tile 0
    kf[0][mt] = *(const bf16x8*)(Kg + (size_t)(mt * 16 + n) * 32 + g * 8);

#pragma unroll
  for (int t = 0; t < 16; t++) {  // fully unrolled: all frag indices static
    const int cur = t & 1, nxt = cur ^ 1;
    const int k0 = t * 64;

    // V frags for this tile (consumed after softmax — latency hidden)
#pragma unroll
    for (int i = 0; i < 4; i++)
      vf[i] = *(const bf16x8*)(Vg + (size_t)((i & 1) * 16 + n) * 1024 + k0 +
                               (i >> 1) * 32 + g * 8);
    // K frag prefetch for tile t+1
    if (t < 15) {
#pragma unroll
      for (int mt = 0; mt < 4; mt++)
        kf[nxt][mt] = *(const bf16x8*)(Kg + (size_t)(k0 + 64 + mt * 16 + n) * 32 +
                                       g * 8);
    }

    // S^T[k][q] = K·Q^T ; C-layout: q = lane&15, k = mt*16 + g*4 + r
    f32x4 s[4];
    __builtin_amdgcn_s_setprio(1);
#pragma unroll
    for (int mt = 0; mt < 4; mt++)
      s[mt] = __builtin_amdgcn_mfma_f32_16x16x32_bf16(
          kf[cur][mt], qf, (f32x4){0.f, 0.f, 0.f, 0.f}, 0, 0, 0);
    __builtin_amdgcn_s_setprio(0);

    // + RPE bias from LDS table (4 consecutive entries per (mt,g))
#pragma unroll
    for (int mt = 0; mt < 4; mt++) {
      int kb = k0 + mt * 16 + g * 4;
      int ib = tbase + (31 - (kb >> 5)) * 63 + (31 - (kb & 31));
      s[mt][0] += th[ib];
      s[mt][1] += th[ib - 1];
      s[mt][2] += th[ib - 2];
      s[mt][3] += th[ib - 3];
    }

    // online softmax: max across regs + g-groups; l stays g-partial
    float mx = -1e30f;
#pragma unroll
    for (int mt = 0; mt < 4; mt++)
#pragma unroll
      for (int r = 0; r < 4; r++) mx = fmaxf(mx, s[mt][r]);
    mx = fmaxf(mx, __shfl_xor(mx, 16, 64));
    mx = fmaxf(mx, __shfl_xor(mx, 32, 64));
    float m_new = fmaxf(m_run, mx);
    float alpha = __expf(m_run - m_new);
    m_run = m_new;

    unsigned short* Pw = cur ? Pw1 : Pw0;
    float ls = 0.f;
#pragma unroll
    for (int mt = 0; mt < 4; mt++) {
#pragma unroll
      for (int r = 0; r < 4; r++) {
        float p = __expf(s[mt][r] - m_new);
        s[mt][r] = p;
        ls += p;
      }
      u16x4 pk = {f2bf(s[mt][0]), f2bf(s[mt][1]), f2bf(s[mt][2]),
                  f2bf(s[mt][3])};
      *(u16x4*)(Pw + n * 68 + mt * 16 + g * 4) = pk;
    }
    l_run = l_run * alpha + ls;

    // O^T rescale + PV (same-wave LDS RAW on Pw: compiler inserts lgkmcnt)
#pragma unroll
    for (int dt = 0; dt < 2; dt++)
#pragma unroll
      for (int r = 0; r < 4; r++) oacc[dt][r] *= alpha;
    __builtin_amdgcn_s_setprio(1);
#pragma unroll
    for (int kt = 0; kt < 2; kt++) {
      bf16x8 pf = *(const bf16x8*)(Pw + n * 68 + kt * 32 + g * 8);
      oacc[0] = __builtin_amdgcn_mfma_f32_16x16x32_bf16(vf[kt * 2 + 0], pf,
                                                        oacc[0], 0, 0, 0);
      oacc[1] = __builtin_amdgcn_mfma_f32_16x16x32_bf16(vf[kt * 2 + 1], pf,
                                                        oacc[1], 0, 0, 0);
    }
    __builtin_amdgcn_s_setprio(0);
  }

  // epilogue: reduce l across g-groups once, normalize, store
  float l = l_run;
  l += __shfl_xor(l, 16, 64);
  l += __shfl_xor(l, 32, 64);
  float invl = 1.f / l;
  unsigned short* ob = out + ((size_t)(b * 1024 + q) * 256) + h * 32;
#pragma unroll
  for (int dt = 0; dt < 2; dt++) {
    u16x4 o4 = {f2bf(oacc[dt][0] * invl), f2bf(oacc[dt][1] * invl),
                f2bf(oacc[dt][2] * invl), f2bf(oacc[dt][3] * invl)};
    *(u16x4*)(ob + dt * 16 + g * 4) = o4;
  }
}

// ---------------------------------------------------------------------------
extern "C" void kernel_launch(void* const* d_in, const int* in_sizes, int n_in,
                              void* d_out, int out_size, void* d_ws, size_t ws_size,
                              hipStream_t stream) {
  const float* x         = (const float*)d_in[0];
  const float* w_embed   = (const float*)d_in[1];
  const float* b_embed   = (const float*)d_in[2];
  const float* cpb_w1    = (const float*)d_in[3];
  const float* cpb_b1    = (const float*)d_in[4];
  const float* cpb_w2    = (const float*)d_in[5];
  const float* w_qkv     = (const float*)d_in[6];
  const float* b_qkv     = (const float*)d_in[7];
  const float* w_proj    = (const float*)d_in[8];
  const float* b_proj    = (const float*)d_in[9];
  const float* w_unembed = (const float*)d_in[10];
  const float* b_unembed = (const float*)d_in[11];
  float* out = (float*)d_out;

  // workspace layout (~105 MB)
  char* w = (char*)d_ws;
  unsigned short* Abig  = (unsigned short*)w; w += (size_t)8192 * 4096 * 2;  // 64 MB
  unsigned short* tok   = (unsigned short*)w; w += (size_t)8192 * 256 * 2;   //  4 MB
  unsigned short* wE    = (unsigned short*)w; w += (size_t)1048576 * 2;      //  2 MB
  unsigned short* wQ    = (unsigned short*)w; w += (size_t)196608 * 2;       // 384 KB
  unsigned short* wP    = (unsigned short*)w; w += (size_t)65536 * 2;        // 128 KB
  unsigned short* wUt   = (unsigned short*)w; w += (size_t)1048576 * 2;      //  2 MB
  float*          tableT= (float*)w;          w += (size_t)32768 * 4;        // 128 KB
  float*          PART  = (float*)w;          w += (size_t)8388608 * 4;      // 32 MB

  // live-range aliases inside PART (partials dead once reduced):
  unsigned short* qkvB  = (unsigned short*)PART;                     // 12 MB
  unsigned short* attno = (unsigned short*)((char*)PART + 12582912); //  4 MB
  unsigned short* z2    = (unsigned short*)((char*)PART + 16777216); //  4 MB
  unsigned short* Qb  = qkvB;
  unsigned short* Kb  = qkvB + 2097152;
  unsigned short* Vtb = qkvB + 2 * 2097152;

  // ---- prep (weights, im2col, RPE table) ----
  cvt_bf16_kernel<<<512, 256, 0, stream>>>(w_embed, wE, 131072);
  cvt_bf16_kernel<<<96, 256, 0, stream>>>(w_qkv, wQ, 24576);
  cvt_bf16_kernel<<<32, 256, 0, stream>>>(w_proj, wP, 8192);
  transpose_cvt_kernel<<<dim3(128, 8), 256, 0, stream>>>(w_unembed, wUt);
  im2col_bf16_kernel<<<8192, 256, 0, stream>>>(x, Abig);
  rpe_table_kernel<<<16, 256, 0, stream>>>(cpb_w1, cpb_b1, cpb_w2, tableT);

  // ---- embed: split-K x4 -> f32 partials (PART) -> reduce(+bias) -> tok ----
  gemm_mfma_kernel<4><<<dim3(2, 64, 4), 256, 0, stream>>>(
      Abig, wE, nullptr, PART, 8192, 256, 1024, 4096, 4096, 256);
  splitk_reduce_kernel<<<1024, 256, 0, stream>>>(PART, b_embed, tok);

  // ---- qkv + fused split/scale/transpose into Qb/Kb/Vtb ----
  gemm_mfma_kernel<3><<<dim3(6, 64), 256, 0, stream>>>(
      tok, wQ, b_qkv, qkvB, 8192, 768, 256, 256, 256, 0);

  // ---- attention (barrier-free, inline RPE gather) ----
  attn_mfma_kernel<<<512, 512, 0, stream>>>(Qb, Kb, Vtb, tableT, attno);

  // ---- proj: split-K x4 (partials in dead Abig) -> reduce -> z2 ----
  gemm_mfma_kernel<4><<<dim3(2, 64, 4), 256, 0, stream>>>(
      attno, wP, nullptr, (float*)Abig, 8192, 256, 64, 256, 256, 256);
  splitk_reduce_kernel<<<1024, 256, 0, stream>>>((float*)Abig, b_proj, z2);

  // ---- unembed + fused col2im ----
  gemm_mfma_kernel<2><<<dim3(32, 64), 256, 0, stream>>>(
      z2, wUt, b_unembed, out, 8192, 4096, 256, 256, 256, 0);
}

// Round 4
// 496.050 us; speedup vs baseline: 1.1337x; 1.1034x over previous
//
#include <hip/hip_runtime.h>
#include <cstdint>
#include <cstddef>

// PatchAttention on MI355X — round 7:
//  - attention: rolled 8x2 pipelined loop (named kfA/kfB frag sets, static
//    indexing) to kill the scratch spills round 6 exposed (WRITE_SIZE 91 MB).
//  - embed GEMM: im2col fused into A-staging (read x f32 directly, convert
//    in-reg, ds_write); im2col kernel + 64 MB A buffer round-trip deleted.
//    XCD-pairing swizzle so each x row-panel is HBM-fetched once.

typedef __bf16 bf16x8 __attribute__((ext_vector_type(8)));
typedef float f32x4 __attribute__((ext_vector_type(4)));
typedef unsigned short u16x4 __attribute__((ext_vector_type(4)));

__device__ __forceinline__ unsigned short f2bf(float f) {
  unsigned u = __builtin_bit_cast(unsigned, f);
  u += 0x7fffu + ((u >> 16) & 1u);  // round-to-nearest-even
  return (unsigned short)(u >> 16);
}
__device__ __forceinline__ float bf2f(unsigned short u) {
  return __builtin_bit_cast(float, ((unsigned)u) << 16);
}

// async 16B global -> LDS (wave-uniform base + lane*16 layout)
__device__ __forceinline__ void async_ld16(const void* g, void* l) {
  __builtin_amdgcn_global_load_lds(
      (const __attribute__((address_space(1))) void*)g,
      (__attribute__((address_space(3))) void*)l, 16, 0, 0);
}

__device__ __forceinline__ void cvt8_store(unsigned short* dst, float4 a,
                                           float4 b) {
  unsigned short t[8] = {f2bf(a.x), f2bf(a.y), f2bf(a.z), f2bf(a.w),
                         f2bf(b.x), f2bf(b.y), f2bf(b.z), f2bf(b.w)};
  *(uint4*)dst = *(const uint4*)t;
}

// ---------------------------------------------------------------------------
// RPE table: MLP(2 -> 512 -> 8) over the 63x63 grid -> tableT [8][4096] f32.
__global__ __launch_bounds__(256) void rpe_table_kernel(
    const float* __restrict__ w1, const float* __restrict__ b1,
    const float* __restrict__ w2, float* __restrict__ tableT) {
  int t = blockIdx.x * 256 + threadIdx.x;
  if (t >= 3969) return;
  int a = t / 63, c = t - a * 63;
  float rh = (float)(a - 31) * (1.0f / 31.0f);
  float rw = (float)(c - 31) * (1.0f / 31.0f);
  float acc[8];
#pragma unroll
  for (int h = 0; h < 8; h++) acc[h] = 0.f;
  for (int j = 0; j < 512; j++) {
    float hv = fmaxf(rh * w1[2 * j] + rw * w1[2 * j + 1] + b1[j], 0.f);
#pragma unroll
    for (int h = 0; h < 8; h++) acc[h] += hv * w2[h * 512 + j];
  }
#pragma unroll
  for (int h = 0; h < 8; h++) tableT[h * 4096 + t] = acc[h];
}

// ---------------------------------------------------------------------------
// generic fp32 -> bf16 convert, 8 elems/thread
__global__ __launch_bounds__(256) void cvt_bf16_kernel(
    const float* __restrict__ src, unsigned short* __restrict__ dst, int n8) {
  int i = blockIdx.x * 256 + threadIdx.x;
  if (i >= n8) return;
  const float4* s4 = (const float4*)src + (size_t)i * 2;
  float4 a = s4[0], b = s4[1];
  unsigned short t[8] = {f2bf(a.x), f2bf(a.y), f2bf(a.z), f2bf(a.w),
                         f2bf(b.x), f2bf(b.y), f2bf(b.z), f2bf(b.w)};
  *(uint4*)(dst + (size_t)i * 8) = *(const uint4*)t;
}

// transpose+convert: src [256][4096] f32 -> dst [4096][256] bf16
__global__ __launch_bounds__(256) void transpose_cvt_kernel(
    const float* __restrict__ src, unsigned short* __restrict__ dst) {
  __shared__ float tile[32][33];
  int bx = blockIdx.x;
  int by = blockIdx.y;
  int tx = threadIdx.x & 31, ty = threadIdx.x >> 5;
#pragma unroll
  for (int r = 0; r < 32; r += 8)
    tile[ty + r][tx] = src[(size_t)(by * 32 + ty + r) * 4096 + bx * 32 + tx];
  __syncthreads();
#pragma unroll
  for (int r = 0; r < 32; r += 8)
    dst[(size_t)(bx * 32 + ty + r) * 256 + by * 32 + tx] = f2bf(tile[tx][ty + r]);
}

// ---------------------------------------------------------------------------
// splitk reduce: out[8192*256] bf16 = sum_{s<4} part[s][.] + bias[col]
__global__ __launch_bounds__(256) void splitk_reduce_kernel(
    const float* __restrict__ part, const float* __restrict__ bias,
    unsigned short* __restrict__ out) {
  size_t i = ((size_t)blockIdx.x * 256 + threadIdx.x) * 8;
  const float4* p = (const float4*)(part + i);
  const size_t s4 = 2097152 / 4;  // float4 stride per split
  float4 a0 = p[0], a1 = p[1];
#pragma unroll
  for (int s = 1; s < 4; s++) {
    float4 b0 = p[s * s4], b1 = p[s * s4 + 1];
    a0.x += b0.x; a0.y += b0.y; a0.z += b0.z; a0.w += b0.w;
    a1.x += b1.x; a1.y += b1.y; a1.z += b1.z; a1.w += b1.w;
  }
  int col = (int)(i & 255);
  unsigned short t8[8] = {
      f2bf(a0.x + bias[col + 0]), f2bf(a0.y + bias[col + 1]),
      f2bf(a0.z + bias[col + 2]), f2bf(a0.w + bias[col + 3]),
      f2bf(a1.x + bias[col + 4]), f2bf(a1.y + bias[col + 5]),
      f2bf(a1.z + bias[col + 6]), f2bf(a1.w + bias[col + 7])};
  *(uint4*)(out + i) = *(const uint4*)t8;
}

// ---------------------------------------------------------------------------
// Embed GEMM with fused im2col: Cpart[z][8192][256] f32 =
//   x-as-A[8192, z*1024..z*1024+1024] * wE^T.  A-tile staging reads x (f32)
//   directly: chunk (r,ch) covers k = z*1024 + kstep*32 + ch*8 ->
//   (c, p0..p0+1, q0..3); two float4 loads + cvt -> 16 B ds_write.
// Grid: 512 linear blocks; XCD-pairing swizzle keeps both n-tiles of one
// (y,z) panel on one XCD so x is HBM-fetched once.
__global__ __launch_bounds__(256) void gemm_embed_kernel(
    const float* __restrict__ x, const unsigned short* __restrict__ B,
    float* __restrict__ Cpart) {
  __shared__ unsigned short As[2 * 128 * 32];
  __shared__ unsigned short Bs[2 * 128 * 32];
  int tid = threadIdx.x;
  int lane = tid & 63, wave = tid >> 6;

  // swizzle: hw-linear L -> xcd = L&7; pair both n-tiles on same xcd
  int L = blockIdx.x;
  int xcd = L & 7, j = L >> 3;
  int pair = xcd * 32 + (j >> 1);  // 0..255
  int n0 = (j & 1) * 128;
  int z = pair & 3, y = pair >> 2;
  int m0 = y * 128;
  int wm = (wave & 1) * 64, wn = (wave >> 1) * 64;
  int fr = lane & 15, fh = lane >> 4;

  f32x4 acc[4][4];
#pragma unroll
  for (int i = 0; i < 4; i++)
#pragma unroll
    for (int jj = 0; jj < 4; jj++) acc[i][jj] = (f32x4){0.f, 0.f, 0.f, 0.f};

  int f0 = tid, f1 = tid + 256;
  // B staging (bf16 weights [256][4096])
  const unsigned short* Bg0 =
      B + (size_t)(n0 + (f0 >> 2)) * 4096 + z * 1024 + (f0 & 3) * 8;
  const unsigned short* Bg1 =
      B + (size_t)(n0 + (f1 >> 2)) * 4096 + z * 1024 + (f1 & 3) * 8;
  unsigned short* Bl0 = Bs + f0 * 8;
  unsigned short* Bl1 = Bs + f1 * 8;

  // A staging from x: per f, row r=f>>2, chunk ch=f&3
  const float4* x4 = (const float4*)x;
  int r0 = f0 >> 2, ch0 = f0 & 3;
  int m_0 = m0 + r0, b_0 = m_0 >> 10, hp0 = (m_0 >> 5) & 31, wp0 = m_0 & 31;
  int k_0 = z * 1024 + ch0 * 8, c_0 = k_0 >> 4, p_0 = (k_0 >> 2) & 3;
  const float4* xp0 =
      x4 + (size_t)((b_0 * 256 + c_0) * 128 + hp0 * 4 + p_0) * 32 + wp0;
  int r1 = f1 >> 2, ch1 = f1 & 3;
  int m_1 = m0 + r1, b_1 = m_1 >> 10, hp1 = (m_1 >> 5) & 31, wp1 = m_1 & 31;
  int k_1 = z * 1024 + ch1 * 8, c_1 = k_1 >> 4, p_1 = (k_1 >> 2) & 3;
  const float4* xp1 =
      x4 + (size_t)((b_1 * 256 + c_1) * 128 + hp1 * 4 + p_1) * 32 + wp1;
  unsigned short* Al0 = As + f0 * 8;
  unsigned short* Al1 = As + f1 * 8;

  // prologue: tile 0
  float4 a00 = xp0[0], a01 = xp0[32], a10 = xp1[0], a11 = xp1[32];
  xp0 += 8192; xp1 += 8192;  // +32 k = +2 channels
  async_ld16(Bg0, Bl0);
  async_ld16(Bg1, Bl1);
  cvt8_store(Al0, a00, a01);
  cvt8_store(Al1, a10, a11);
  __syncthreads();

  for (int t = 0; t < 32; t++) {
    int cur = (t & 1) << 12, nxt = cur ^ 4096;
    if (t < 31) {  // issue next-tile loads (consumed after MFMA block)
      a00 = xp0[0]; a01 = xp0[32]; a10 = xp1[0]; a11 = xp1[32];
      xp0 += 8192; xp1 += 8192;
      int kn = (t + 1) << 5;
      async_ld16(Bg0 + kn, Bl0 + nxt);
      async_ld16(Bg1 + kn, Bl1 + nxt);
    }
    const unsigned short* Asc = As + cur;
    const unsigned short* Bsc = Bs + cur;
    bf16x8 af[4], bfr[4];
#pragma unroll
    for (int tt = 0; tt < 4; tt++) {
      af[tt] = *(const bf16x8*)(Asc + (wm + tt * 16 + fr) * 32 + fh * 8);
      bfr[tt] = *(const bf16x8*)(Bsc + (wn + tt * 16 + fr) * 32 + fh * 8);
    }
#pragma unroll
    for (int mt = 0; mt < 4; mt++)
#pragma unroll
      for (int nt = 0; nt < 4; nt++)
        acc[mt][nt] = __builtin_amdgcn_mfma_f32_16x16x32_bf16(
            af[mt], bfr[nt], acc[mt][nt], 0, 0, 0);
    if (t < 31) {
      cvt8_store(Al0 + nxt, a00, a01);
      cvt8_store(Al1 + nxt, a10, a11);
    }
    __syncthreads();
  }

  // epilogue: f32 partials
  float* Cp = Cpart + (size_t)z * 2097152;
#pragma unroll
  for (int mt = 0; mt < 4; mt++) {
    int row0 = m0 + wm + mt * 16 + fh * 4;
#pragma unroll
    for (int nt = 0; nt < 4; nt++) {
      int col = n0 + wn + nt * 16 + fr;
#pragma unroll
      for (int r = 0; r < 4; r++)
        Cp[(size_t)(row0 + r) * 256 + col] = acc[mt][nt][r];
    }
  }
}

// ---------------------------------------------------------------------------
// bf16 MFMA GEMM: C[M,N] = A[M,K] * B^T (B given [N,K] bf16) + bias.
// CMODE: 1 = bf16 C, 2 = fused col2im into y[8,256,128,128] f32,
//        3 = fused QKV split, 4 = split-K f32 partials.
template <int CMODE>
__global__ __launch_bounds__(256) void gemm_mfma_kernel(
    const unsigned short* __restrict__ A, const unsigned short* __restrict__ B,
    const float* __restrict__ bias, void* __restrict__ Cv,
    int M, int N, int K, int lda, int ldb, int ldc) {
  __shared__ unsigned short As[2 * 128 * 32];
  __shared__ unsigned short Bs[2 * 128 * 32];
  int tid = threadIdx.x;
  int lane = tid & 63;
  int wave = tid >> 6;
  int m0 = blockIdx.y * 128, n0 = blockIdx.x * 128;
  int wm = (wave & 1) * 64, wn = (wave >> 1) * 64;

  if (CMODE == 4) {
    int s = blockIdx.z;
    A += (size_t)s * K;
    B += (size_t)s * K;
    Cv = (void*)((float*)Cv + (size_t)s * M * N);
  }

  f32x4 acc[4][4];
#pragma unroll
  for (int i = 0; i < 4; i++)
#pragma unroll
    for (int j = 0; j < 4; j++) acc[i][j] = (f32x4){0.f, 0.f, 0.f, 0.f};

  int f0 = tid, f1 = tid + 256;
  const unsigned short* Ag0 = A + (size_t)(m0 + (f0 >> 2)) * lda + (f0 & 3) * 8;
  const unsigned short* Ag1 = A + (size_t)(m0 + (f1 >> 2)) * lda + (f1 & 3) * 8;
  const unsigned short* Bg0 = B + (size_t)(n0 + (f0 >> 2)) * ldb + (f0 & 3) * 8;
  const unsigned short* Bg1 = B + (size_t)(n0 + (f1 >> 2)) * ldb + (f1 & 3) * 8;
  unsigned short* Al0 = As + f0 * 8;
  unsigned short* Al1 = As + f1 * 8;
  unsigned short* Bl0 = Bs + f0 * 8;
  unsigned short* Bl1 = Bs + f1 * 8;

  int fr = lane & 15;
  int fh = lane >> 4;

  int ntiles = K >> 5;
  async_ld16(Ag0, Al0);
  async_ld16(Ag1, Al1);
  async_ld16(Bg0, Bl0);
  async_ld16(Bg1, Bl1);
  __syncthreads();

  for (int t = 0; t < ntiles; t++) {
    int cur = (t & 1) << 12;
    int nxt = cur ^ 4096;
    if (t + 1 < ntiles) {
      int kn = (t + 1) << 5;
      async_ld16(Ag0 + kn, Al0 + nxt);
      async_ld16(Ag1 + kn, Al1 + nxt);
      async_ld16(Bg0 + kn, Bl0 + nxt);
      async_ld16(Bg1 + kn, Bl1 + nxt);
    }
    const unsigned short* Asc = As + cur;
    const unsigned short* Bsc = Bs + cur;
    bf16x8 af[4], bfr[4];
#pragma unroll
    for (int tt = 0; tt < 4; tt++) {
      af[tt] = *(const bf16x8*)(Asc + (wm + tt * 16 + fr) * 32 + fh * 8);
      bfr[tt] = *(const bf16x8*)(Bsc + (wn + tt * 16 + fr) * 32 + fh * 8);
    }
#pragma unroll
    for (int mt = 0; mt < 4; mt++)
#pragma unroll
      for (int nt = 0; nt < 4; nt++)
        acc[mt][nt] = __builtin_amdgcn_mfma_f32_16x16x32_bf16(
            af[mt], bfr[nt], acc[mt][nt], 0, 0, 0);
    __syncthreads();
  }

#pragma unroll
  for (int mt = 0; mt < 4; mt++) {
    int row0 = m0 + wm + mt * 16 + fh * 4;
    if (CMODE == 2) {
      int b = row0 >> 10, hp = (row0 >> 5) & 31, wp = row0 & 31;
      size_t rowoff0 = (size_t)b * 4194304 + hp * 512 + wp * 4;
      float* y = (float*)Cv;
#pragma unroll
      for (int nt = 0; nt < 4; nt++) {
        int col = n0 + wn + nt * 16 + fr;
        int o = col >> 4, p = (col >> 2) & 3, q = col & 3;
        size_t coloff = (size_t)o * 16384 + p * 128 + q;
        float bv = bias[o];
#pragma unroll
        for (int r = 0; r < 4; r++)
          y[rowoff0 + r * 4 + coloff] = acc[mt][nt][r] + bv;
      }
    } else if (CMODE == 3) {
      unsigned short* base = (unsigned short*)Cv;
#pragma unroll
      for (int nt = 0; nt < 4; nt++) {
        int col = n0 + wn + nt * 16 + fr;
        int which = col >> 8, hh = (col >> 5) & 7, d = col & 31;
        float bv = bias[col];
#pragma unroll
        for (int r = 0; r < 4; r++) {
          int row = row0 + r;
          int bb = row >> 10, nn = row & 1023;
          int bh = bb * 8 + hh;
          float v = acc[mt][nt][r] + bv;
          if (which == 0) v *= 0.17677669529663687f;  // 1/sqrt(32)
          size_t addr;
          if (which < 2)
            addr = (size_t)which * 2097152 + ((size_t)bh * 1024 + nn) * 32 + d;
          else
            addr = (size_t)2 * 2097152 + (size_t)bh * 32768 + (size_t)d * 1024 + nn;
          base[addr] = f2bf(v);
        }
      }
    } else if (CMODE == 4) {
      float* Cp = (float*)Cv;
#pragma unroll
      for (int nt = 0; nt < 4; nt++) {
        int col = n0 + wn + nt * 16 + fr;
#pragma unroll
        for (int r = 0; r < 4; r++)
          Cp[(size_t)(row0 + r) * ldc + col] = acc[mt][nt][r];
      }
    } else {
#pragma unroll
      for (int nt = 0; nt < 4; nt++) {
        int col = n0 + wn + nt * 16 + fr;
        float bv = bias ? bias[col] : 0.f;
        unsigned short* C = (unsigned short*)Cv;
#pragma unroll
        for (int r = 0; r < 4; r++)
          C[(size_t)(row0 + r) * ldc + col] = f2bf(acc[mt][nt][r] + bv);
      }
    }
  }
}

// ---------------------------------------------------------------------------
// MFMA flash attention, round 7 — barrier-free, ROLLED 8x2 pipelined loop.
// Named kfA/kfB fragment sets (static indices, ~100 VGPR live) to eliminate
// the round-6 scratch spills. K/V frags direct global->reg (L2-resident via
// h=blk&7 XCD mapping). LDS: RPE table + per-wave double-buffered P scratch.
__global__ __launch_bounds__(512) void attn_mfma_kernel(
    const unsigned short* __restrict__ Qb, const unsigned short* __restrict__ Kb,
    const unsigned short* __restrict__ Vtb,
    const float* __restrict__ tableT,
    unsigned short* __restrict__ out) {
  __shared__ float th[3972];                 // per-head RPE table column
  __shared__ unsigned short Ps[2][8][1088];  // [half][wave][16*68] P scratch

  int tid = threadIdx.x;
  int lane = tid & 63, w = tid >> 6;
  int n = lane & 15, g = lane >> 4;
  int blk = blockIdx.x;
  int h = blk & 7, b = (blk >> 3) & 7, qt = blk >> 6;
  int bh = b * 8 + h;
  int q0 = qt * 128;

  const unsigned short* Qg = Qb + ((size_t)bh * 1024 + q0) * 32;
  const unsigned short* Kg = Kb + (size_t)bh * 1024 * 32;
  const unsigned short* Vg = Vtb + (size_t)bh * 32 * 1024;
  const float* tg = tableT + (size_t)h * 4096;

  for (int i = tid; i < 3969; i += 512) th[i] = tg[i];
  bf16x8 qf = *(const bf16x8*)(Qg + (size_t)(w * 16 + n) * 32 + g * 8);
  __syncthreads();  // table ready — the only barrier

  f32x4 oacc[2];
  oacc[0] = (f32x4){0.f, 0.f, 0.f, 0.f};
  oacc[1] = (f32x4){0.f, 0.f, 0.f, 0.f};
  float m_run = -1e30f, l_run = 0.f;  // l_run g-partial, reduced at end

  int q = q0 + w * 16 + n;
  int tbase = (q >> 5) * 63 + (q & 31) + 1984;  // + (31*63+31)

  unsigned short* PwA = &Ps[0][w][0];
  unsigned short* PwB = &Ps[1][w][0];

  bf16x8 kfA[4], kfB[4];
#pragma unroll
  for (int mt = 0; mt < 4; mt++)
    kfA[mt] = *(const bf16x8*)(Kg + (size_t)(mt * 16 + n) * 32 + g * 8);

  auto half_step = [&](const bf16x8 (&kf)[4], int k0, unsigned short* Pw) {
    // V frags (consumed after softmax — latency hidden under QK+softmax)
    bf16x8 vf[4];
#pragma unroll
    for (int i = 0; i < 4; i++)
      vf[i] = *(const bf16x8*)(Vg + (size_t)((i & 1) * 16 + n) * 1024 + k0 +
                               (i >> 1) * 32 + g * 8);

    // S^T[k][q] = K·Q^T ; C-layout: q = lane&15, k = mt*16 + g*4 + r
    f32x4 s[4];
    __builtin_amdgcn_s_setprio(1);
#pragma unroll
    for (int mt = 0; mt < 4; mt++)
      s[mt] = __builtin_amdgcn_mfma_f32_16x16x32_bf16(
          kf[mt], qf, (f32x4){0.f, 0.f, 0.f, 0.f}, 0, 0, 0);
    __builtin_amdgcn_s_setprio(0);

    // + RPE bias from LDS table (4 consecutive entries per (mt,g))
#pragma unroll
    for (int mt = 0; mt < 4; mt++) {
      int kb = k0 + mt * 16 + g * 4;
      int ib = tbase - (kb >> 5) * 63 - (kb & 31);
      s[mt][0] += th[ib];
      s[mt][1] += th[ib - 1];
      s[mt][2] += th[ib - 2];
      s[mt][3] += th[ib - 3];
    }

    // online softmax (max over regs + g-groups; l stays g-partial)
    float mx = -1e30f;
#pragma unroll
    for (int mt = 0; mt < 4; mt++)
#pragma unroll
      for (int r = 0; r < 4; r++) mx = fmaxf(mx, s[mt][r]);
    mx = fmaxf(mx, __shfl_xor(mx, 16, 64));
    mx = fmaxf(mx, __shfl_xor(mx, 32, 64));
    float m_new = fmaxf(m_run, mx);
    float alpha = __expf(m_run - m_new);
    m_run = m_new;

    float ls = 0.f;
#pragma unroll
    for (int mt = 0; mt < 4; mt++) {
#pragma unroll
      for (int r = 0; r < 4; r++) {
        float p = __expf(s[mt][r] - m_new);
        s[mt][r] = p;
        ls += p;
      }
      u16x4 pk = {f2bf(s[mt][0]), f2bf(s[mt][1]), f2bf(s[mt][2]),
                  f2bf(s[mt][3])};
      *(u16x4*)(Pw + n * 68 + mt * 16 + g * 4) = pk;
    }
    l_run = l_run * alpha + ls;

    // O^T rescale + PV (same-wave LDS RAW on Pw: lgkmcnt ordering)
#pragma unroll
    for (int dt = 0; dt < 2; dt++)
#pragma unroll
      for (int r = 0; r < 4; r++) oacc[dt][r] *= alpha;
    __builtin_amdgcn_s_setprio(1);
#pragma unroll
    for (int kt = 0; kt < 2; kt++) {
      bf16x8 pf = *(const bf16x8*)(Pw + n * 68 + kt * 32 + g * 8);
      oacc[0] = __builtin_amdgcn_mfma_f32_16x16x32_bf16(vf[kt * 2 + 0], pf,
                                                        oacc[0], 0, 0, 0);
      oacc[1] = __builtin_amdgcn_mfma_f32_16x16x32_bf16(vf[kt * 2 + 1], pf,
                                                        oacc[1], 0, 0, 0);
    }
    __builtin_amdgcn_s_setprio(0);
  };

  for (int tt = 0; tt < 8; tt++) {
    int k0 = tt * 128;
    // prefetch K frags for odd half (hidden under half A)
#pragma unroll
    for (int mt = 0; mt < 4; mt++)
      kfB[mt] = *(const bf16x8*)(Kg + (size_t)(k0 + 64 + mt * 16 + n) * 32 +
                                 g * 8);
    half_step(kfA, k0, PwA);
    if (tt < 7) {  // prefetch K frags for next even half (hidden under half B)
#pragma unroll
      for (int mt = 0; mt < 4; mt++)
        kfA[mt] = *(const bf16x8*)(Kg + (size_t)(k0 + 128 + mt * 16 + n) * 32 +
                                   g * 8);
    }
    half_step(kfB, k0 + 64, PwB);
  }

  // epilogue: reduce l across g-groups, normalize, store
  float l = l_run;
  l += __shfl_xor(l, 16, 64);
  l += __shfl_xor(l, 32, 64);
  float invl = 1.f / l;
  unsigned short* ob = out + ((size_t)(b * 1024 + q) * 256) + h * 32;
#pragma unroll
  for (int dt = 0; dt < 2; dt++) {
    u16x4 o4 = {f2bf(oacc[dt][0] * invl), f2bf(oacc[dt][1] * invl),
                f2bf(oacc[dt][2] * invl), f2bf(oacc[dt][3] * invl)};
    *(u16x4*)(ob + dt * 16 + g * 4) = o4;
  }
}

// ---------------------------------------------------------------------------
extern "C" void kernel_launch(void* const* d_in, const int* in_sizes, int n_in,
                              void* d_out, int out_size, void* d_ws, size_t ws_size,
                              hipStream_t stream) {
  const float* x         = (const float*)d_in[0];
  const float* w_embed   = (const float*)d_in[1];
  const float* b_embed   = (const float*)d_in[2];
  const float* cpb_w1    = (const float*)d_in[3];
  const float* cpb_b1    = (const float*)d_in[4];
  const float* cpb_w2    = (const float*)d_in[5];
  const float* w_qkv     = (const float*)d_in[6];
  const float* b_qkv     = (const float*)d_in[7];
  const float* w_proj    = (const float*)d_in[8];
  const float* b_proj    = (const float*)d_in[9];
  const float* w_unembed = (const float*)d_in[10];
  const float* b_unembed = (const float*)d_in[11];
  float* out = (float*)d_out;

  // workspace layout
  char* w = (char*)d_ws;
  float*          ProjP = (float*)w;          w += (size_t)8388608 * 4;      // 32 MB (proj partials)
  unsigned short* tok   = (unsigned short*)w; w += (size_t)8192 * 256 * 2;   //  4 MB
  unsigned short* wE    = (unsigned short*)w; w += (size_t)1048576 * 2;      //  2 MB
  unsigned short* wQ    = (unsigned short*)w; w += (size_t)196608 * 2;       // 384 KB
  unsigned short* wP    = (unsigned short*)w; w += (size_t)65536 * 2;        // 128 KB
  unsigned short* wUt   = (unsigned short*)w; w += (size_t)1048576 * 2;      //  2 MB
  float*          tableT= (float*)w;          w += (size_t)32768 * 4;        // 128 KB
  float*          PART  = (float*)w;          w += (size_t)8388608 * 4;      // 32 MB

  // live-range aliases inside PART (embed partials dead once reduced):
  unsigned short* qkvB  = (unsigned short*)PART;                     // 12 MB
  unsigned short* attno = (unsigned short*)((char*)PART + 12582912); //  4 MB
  unsigned short* z2    = (unsigned short*)((char*)PART + 16777216); //  4 MB
  unsigned short* Qb  = qkvB;
  unsigned short* Kb  = qkvB + 2097152;
  unsigned short* Vtb = qkvB + 2 * 2097152;

  // ---- prep (weights, RPE table) ----
  cvt_bf16_kernel<<<512, 256, 0, stream>>>(w_embed, wE, 131072);
  cvt_bf16_kernel<<<96, 256, 0, stream>>>(w_qkv, wQ, 24576);
  cvt_bf16_kernel<<<32, 256, 0, stream>>>(w_proj, wP, 8192);
  transpose_cvt_kernel<<<dim3(128, 8), 256, 0, stream>>>(w_unembed, wUt);
  rpe_table_kernel<<<16, 256, 0, stream>>>(cpb_w1, cpb_b1, cpb_w2, tableT);

  // ---- embed: fused-im2col split-K x4 -> f32 partials -> reduce -> tok ----
  gemm_embed_kernel<<<512, 256, 0, stream>>>(x, wE, PART);
  splitk_reduce_kernel<<<1024, 256, 0, stream>>>(PART, b_embed, tok);

  // ---- qkv + fused split/scale/transpose into Qb/Kb/Vtb ----
  gemm_mfma_kernel<3><<<dim3(6, 64), 256, 0, stream>>>(
      tok, wQ, b_qkv, qkvB, 8192, 768, 256, 256, 256, 0);

  // ---- attention (barrier-free, rolled 8x2) ----
  attn_mfma_kernel<<<512, 512, 0, stream>>>(Qb, Kb, Vtb, tableT, attno);

  // ---- proj: split-K x4 -> reduce -> z2 ----
  gemm_mfma_kernel<4><<<dim3(2, 64, 4), 256, 0, stream>>>(
      attno, wP, nullptr, ProjP, 8192, 256, 64, 256, 256, 256);
  splitk_reduce_kernel<<<1024, 256, 0, stream>>>(ProjP, b_proj, z2);

  // ---- unembed + fused col2im ----
  gemm_mfma_kernel<2><<<dim3(32, 64), 256, 0, stream>>>(
      z2, wUt, b_unembed, out, 8192, 4096, 256, 256, 256, 0);
}

// Round 6
// 494.129 us; speedup vs baseline: 1.1382x; 1.0039x over previous
//
#include <hip/hip_runtime.h>
#include <cstdint>
#include <cstddef>

// PatchAttention on MI355X — round 8 (resubmit; prior bench was an infra
// failure: "container failed twice", no correctness/profile data):
//  - embed GEMM rewritten BARRIER-FREE (the round-6/7 attention lesson):
//    A (fused im2col from f32 x) and B (wE, L2-resident) fragments loaded
//    directly global->reg per wave; no LDS, no __syncthreads, no vmcnt(0)
//    drain; 2-set named register pipeline (static indices, no scratch).
//  - everything else carried from round 7.

typedef __bf16 bf16x8 __attribute__((ext_vector_type(8)));
typedef float f32x4 __attribute__((ext_vector_type(4)));
typedef unsigned short u16x4 __attribute__((ext_vector_type(4)));

__device__ __forceinline__ unsigned short f2bf(float f) {
  unsigned u = __builtin_bit_cast(unsigned, f);
  u += 0x7fffu + ((u >> 16) & 1u);  // round-to-nearest-even
  return (unsigned short)(u >> 16);
}
__device__ __forceinline__ float bf2f(unsigned short u) {
  return __builtin_bit_cast(float, ((unsigned)u) << 16);
}

// async 16B global -> LDS (wave-uniform base + lane*16 layout)
__device__ __forceinline__ void async_ld16(const void* g, void* l) {
  __builtin_amdgcn_global_load_lds(
      (const __attribute__((address_space(1))) void*)g,
      (__attribute__((address_space(3))) void*)l, 16, 0, 0);
}

__device__ __forceinline__ bf16x8 cvt8f(float4 a, float4 b) {
  unsigned short t[8] = {f2bf(a.x), f2bf(a.y), f2bf(a.z), f2bf(a.w),
                         f2bf(b.x), f2bf(b.y), f2bf(b.z), f2bf(b.w)};
  return *(const bf16x8*)t;
}

// ---------------------------------------------------------------------------
// RPE table: MLP(2 -> 512 -> 8) over the 63x63 grid -> tableT [8][4096] f32.
__global__ __launch_bounds__(256) void rpe_table_kernel(
    const float* __restrict__ w1, const float* __restrict__ b1,
    const float* __restrict__ w2, float* __restrict__ tableT) {
  int t = blockIdx.x * 256 + threadIdx.x;
  if (t >= 3969) return;
  int a = t / 63, c = t - a * 63;
  float rh = (float)(a - 31) * (1.0f / 31.0f);
  float rw = (float)(c - 31) * (1.0f / 31.0f);
  float acc[8];
#pragma unroll
  for (int h = 0; h < 8; h++) acc[h] = 0.f;
  for (int j = 0; j < 512; j++) {
    float hv = fmaxf(rh * w1[2 * j] + rw * w1[2 * j + 1] + b1[j], 0.f);
#pragma unroll
    for (int h = 0; h < 8; h++) acc[h] += hv * w2[h * 512 + j];
  }
#pragma unroll
  for (int h = 0; h < 8; h++) tableT[h * 4096 + t] = acc[h];
}

// ---------------------------------------------------------------------------
// generic fp32 -> bf16 convert, 8 elems/thread
__global__ __launch_bounds__(256) void cvt_bf16_kernel(
    const float* __restrict__ src, unsigned short* __restrict__ dst, int n8) {
  int i = blockIdx.x * 256 + threadIdx.x;
  if (i >= n8) return;
  const float4* s4 = (const float4*)src + (size_t)i * 2;
  float4 a = s4[0], b = s4[1];
  unsigned short t[8] = {f2bf(a.x), f2bf(a.y), f2bf(a.z), f2bf(a.w),
                         f2bf(b.x), f2bf(b.y), f2bf(b.z), f2bf(b.w)};
  *(uint4*)(dst + (size_t)i * 8) = *(const uint4*)t;
}

// transpose+convert: src [256][4096] f32 -> dst [4096][256] bf16
__global__ __launch_bounds__(256) void transpose_cvt_kernel(
    const float* __restrict__ src, unsigned short* __restrict__ dst) {
  __shared__ float tile[32][33];
  int bx = blockIdx.x;
  int by = blockIdx.y;
  int tx = threadIdx.x & 31, ty = threadIdx.x >> 5;
#pragma unroll
  for (int r = 0; r < 32; r += 8)
    tile[ty + r][tx] = src[(size_t)(by * 32 + ty + r) * 4096 + bx * 32 + tx];
  __syncthreads();
#pragma unroll
  for (int r = 0; r < 32; r += 8)
    dst[(size_t)(bx * 32 + ty + r) * 256 + by * 32 + tx] = f2bf(tile[tx][ty + r]);
}

// ---------------------------------------------------------------------------
// splitk reduce: out[8192*256] bf16 = sum_{s<4} part[s][.] + bias[col]
__global__ __launch_bounds__(256) void splitk_reduce_kernel(
    const float* __restrict__ part, const float* __restrict__ bias,
    unsigned short* __restrict__ out) {
  size_t i = ((size_t)blockIdx.x * 256 + threadIdx.x) * 8;
  const float4* p = (const float4*)(part + i);
  const size_t s4 = 2097152 / 4;  // float4 stride per split
  float4 a0 = p[0], a1 = p[1];
#pragma unroll
  for (int s = 1; s < 4; s++) {
    float4 b0 = p[s * s4], b1 = p[s * s4 + 1];
    a0.x += b0.x; a0.y += b0.y; a0.z += b0.z; a0.w += b0.w;
    a1.x += b1.x; a1.y += b1.y; a1.z += b1.z; a1.w += b1.w;
  }
  int col = (int)(i & 255);
  unsigned short t8[8] = {
      f2bf(a0.x + bias[col + 0]), f2bf(a0.y + bias[col + 1]),
      f2bf(a0.z + bias[col + 2]), f2bf(a0.w + bias[col + 3]),
      f2bf(a1.x + bias[col + 4]), f2bf(a1.y + bias[col + 5]),
      f2bf(a1.z + bias[col + 6]), f2bf(a1.w + bias[col + 7])};
  *(uint4*)(out + i) = *(const uint4*)t8;
}

// ---------------------------------------------------------------------------
// Embed GEMM, fused im2col, BARRIER-FREE: Cpart[z][8192][256] f32 =
//   x-as-A[8192, z*1024 .. +1024] * wE^T.  Per-wave 64x64 output quadrant;
//   A frags read straight from x (f32, two float4 per frag, cvt in-reg),
//   B frags read straight from wE bf16 (L2-resident).  Two named register
//   sets pipeline one k-step ahead; no LDS, no __syncthreads.
// Grid: 512 linear blocks; XCD-pairing swizzle keeps both n-tiles of one
// (y,z) panel on one XCD so x is HBM-fetched once.
__global__ __launch_bounds__(256, 2) void gemm_embed_kernel(
    const float* __restrict__ x, const unsigned short* __restrict__ B,
    float* __restrict__ Cpart) {
  int tid = threadIdx.x;
  int lane = tid & 63, wave = tid >> 6;

  int L = blockIdx.x;
  int xcd = L & 7, j = L >> 3;
  int pair = xcd * 32 + (j >> 1);  // 0..255
  int n0 = (j & 1) * 128;
  int z = pair & 3, y = pair >> 2;
  int m0 = y * 128;
  int wm = (wave & 1) * 64, wn = (wave >> 1) * 64;
  int fr = lane & 15, fh = lane >> 4;

  f32x4 acc[4][4];
#pragma unroll
  for (int i = 0; i < 4; i++)
#pragma unroll
    for (int jj = 0; jj < 4; jj++) acc[i][jj] = (f32x4){0.f, 0.f, 0.f, 0.f};

  // per-lane A row pointers (frag tt = rows wm+tt*16+fr, k-chunk fh*8):
  // k = z*1024 + t*32 + fh*8 -> c = z*64 + 2t + (fh>>1), p0 = (2*fh)&3,
  // frag = x[b][c][hp*4+p0][wp*4..+3] and p0+1 row (+32 float4).
  const float4* x4 = (const float4*)x;
  int c0 = z * 64 + (fh >> 1);
  int p0 = (fh * 2) & 3;
  const float4* xp[4];
#pragma unroll
  for (int tt = 0; tt < 4; tt++) {
    int m = m0 + wm + tt * 16 + fr;
    int b_ = m >> 10, hp = (m >> 5) & 31, wp = m & 31;
    xp[tt] = x4 + (size_t)((b_ * 256 + c0) * 128 + hp * 4 + p0) * 32 + wp;
  }
  // per-lane B frag pointers: row n0+wn+tt*16+fr, k = z*1024 + t*32 + fh*8
  const unsigned short* bp[4];
#pragma unroll
  for (int tt = 0; tt < 4; tt++)
    bp[tt] = B + (size_t)(n0 + wn + tt * 16 + fr) * 4096 + z * 1024 + fh * 8;

  float4 aA[8], aB[8];
  bf16x8 bA[4], bB[4];

  // AOFF in float4 units: one k-step = 2 channels = 2*128*32 = 8192
#define LOADF(areg, breg, AOFF, BOFF)                  \
  {                                                    \
    _Pragma("unroll") for (int tt = 0; tt < 4; tt++) { \
      areg[2 * tt] = xp[tt][AOFF];                     \
      areg[2 * tt + 1] = xp[tt][AOFF + 32];            \
      breg[tt] = *(const bf16x8*)(bp[tt] + BOFF);      \
    }                                                  \
  }

  auto compute = [&](float4 (&a)[8], bf16x8 (&bfr)[4]) {
    bf16x8 af[4];
#pragma unroll
    for (int tt = 0; tt < 4; tt++) af[tt] = cvt8f(a[2 * tt], a[2 * tt + 1]);
    __builtin_amdgcn_s_setprio(1);
#pragma unroll
    for (int mt = 0; mt < 4; mt++)
#pragma unroll
      for (int nt = 0; nt < 4; nt++)
        acc[mt][nt] = __builtin_amdgcn_mfma_f32_16x16x32_bf16(
            af[mt], bfr[nt], acc[mt][nt], 0, 0, 0);
    __builtin_amdgcn_s_setprio(0);
  };

  LOADF(aA, bA, 0, 0);                  // t = 0
  for (int it = 0; it < 16; it++) {
    LOADF(aB, bB, 8192, 32);            // t = 2it+1 (hidden under compute A)
    compute(aA, bA);
    if (it < 15) LOADF(aA, bA, 16384, 64);  // t = 2it+2 (hidden under B)
    compute(aB, bB);
#pragma unroll
    for (int tt = 0; tt < 4; tt++) { xp[tt] += 16384; bp[tt] += 64; }
  }
#undef LOADF

  // epilogue: f32 partials (C/D layout col = lane&15, row = (lane>>4)*4 + r)
  float* Cp = Cpart + (size_t)z * 2097152;
#pragma unroll
  for (int mt = 0; mt < 4; mt++) {
    int row0 = m0 + wm + mt * 16 + fh * 4;
#pragma unroll
    for (int nt = 0; nt < 4; nt++) {
      int col = n0 + wn + nt * 16 + fr;
#pragma unroll
      for (int r = 0; r < 4; r++)
        Cp[(size_t)(row0 + r) * 256 + col] = acc[mt][nt][r];
    }
  }
}

// ---------------------------------------------------------------------------
// bf16 MFMA GEMM: C[M,N] = A[M,K] * B^T (B given [N,K] bf16) + bias.
// CMODE: 1 = bf16 C, 2 = fused col2im into y[8,256,128,128] f32,
//        3 = fused QKV split, 4 = split-K f32 partials.
template <int CMODE>
__global__ __launch_bounds__(256) void gemm_mfma_kernel(
    const unsigned short* __restrict__ A, const unsigned short* __restrict__ B,
    const float* __restrict__ bias, void* __restrict__ Cv,
    int M, int N, int K, int lda, int ldb, int ldc) {
  __shared__ unsigned short As[2 * 128 * 32];
  __shared__ unsigned short Bs[2 * 128 * 32];
  int tid = threadIdx.x;
  int lane = tid & 63;
  int wave = tid >> 6;
  int m0 = blockIdx.y * 128, n0 = blockIdx.x * 128;
  int wm = (wave & 1) * 64, wn = (wave >> 1) * 64;

  if (CMODE == 4) {
    int s = blockIdx.z;
    A += (size_t)s * K;
    B += (size_t)s * K;
    Cv = (void*)((float*)Cv + (size_t)s * M * N);
  }

  f32x4 acc[4][4];
#pragma unroll
  for (int i = 0; i < 4; i++)
#pragma unroll
    for (int j = 0; j < 4; j++) acc[i][j] = (f32x4){0.f, 0.f, 0.f, 0.f};

  int f0 = tid, f1 = tid + 256;
  const unsigned short* Ag0 = A + (size_t)(m0 + (f0 >> 2)) * lda + (f0 & 3) * 8;
  const unsigned short* Ag1 = A + (size_t)(m0 + (f1 >> 2)) * lda + (f1 & 3) * 8;
  const unsigned short* Bg0 = B + (size_t)(n0 + (f0 >> 2)) * ldb + (f0 & 3) * 8;
  const unsigned short* Bg1 = B + (size_t)(n0 + (f1 >> 2)) * ldb + (f1 & 3) * 8;
  unsigned short* Al0 = As + f0 * 8;
  unsigned short* Al1 = As + f1 * 8;
  unsigned short* Bl0 = Bs + f0 * 8;
  unsigned short* Bl1 = Bs + f1 * 8;

  int fr = lane & 15;
  int fh = lane >> 4;

  int ntiles = K >> 5;
  async_ld16(Ag0, Al0);
  async_ld16(Ag1, Al1);
  async_ld16(Bg0, Bl0);
  async_ld16(Bg1, Bl1);
  __syncthreads();

  for (int t = 0; t < ntiles; t++) {
    int cur = (t & 1) << 12;
    int nxt = cur ^ 4096;
    if (t + 1 < ntiles) {
      int kn = (t + 1) << 5;
      async_ld16(Ag0 + kn, Al0 + nxt);
      async_ld16(Ag1 + kn, Al1 + nxt);
      async_ld16(Bg0 + kn, Bl0 + nxt);
      async_ld16(Bg1 + kn, Bl1 + nxt);
    }
    const unsigned short* Asc = As + cur;
    const unsigned short* Bsc = Bs + cur;
    bf16x8 af[4], bfr[4];
#pragma unroll
    for (int tt = 0; tt < 4; tt++) {
      af[tt] = *(const bf16x8*)(Asc + (wm + tt * 16 + fr) * 32 + fh * 8);
      bfr[tt] = *(const bf16x8*)(Bsc + (wn + tt * 16 + fr) * 32 + fh * 8);
    }
#pragma unroll
    for (int mt = 0; mt < 4; mt++)
#pragma unroll
      for (int nt = 0; nt < 4; nt++)
        acc[mt][nt] = __builtin_amdgcn_mfma_f32_16x16x32_bf16(
            af[mt], bfr[nt], acc[mt][nt], 0, 0, 0);
    __syncthreads();
  }

#pragma unroll
  for (int mt = 0; mt < 4; mt++) {
    int row0 = m0 + wm + mt * 16 + fh * 4;
    if (CMODE == 2) {
      int b = row0 >> 10, hp = (row0 >> 5) & 31, wp = row0 & 31;
      size_t rowoff0 = (size_t)b * 4194304 + hp * 512 + wp * 4;
      float* y = (float*)Cv;
#pragma unroll
      for (int nt = 0; nt < 4; nt++) {
        int col = n0 + wn + nt * 16 + fr;
        int o = col >> 4, p = (col >> 2) & 3, q = col & 3;
        size_t coloff = (size_t)o * 16384 + p * 128 + q;
        float bv = bias[o];
#pragma unroll
        for (int r = 0; r < 4; r++)
          y[rowoff0 + r * 4 + coloff] = acc[mt][nt][r] + bv;
      }
    } else if (CMODE == 3) {
      unsigned short* base = (unsigned short*)Cv;
#pragma unroll
      for (int nt = 0; nt < 4; nt++) {
        int col = n0 + wn + nt * 16 + fr;
        int which = col >> 8, hh = (col >> 5) & 7, d = col & 31;
        float bv = bias[col];
#pragma unroll
        for (int r = 0; r < 4; r++) {
          int row = row0 + r;
          int bb = row >> 10, nn = row & 1023;
          int bh = bb * 8 + hh;
          float v = acc[mt][nt][r] + bv;
          if (which == 0) v *= 0.17677669529663687f;  // 1/sqrt(32)
          size_t addr;
          if (which < 2)
            addr = (size_t)which * 2097152 + ((size_t)bh * 1024 + nn) * 32 + d;
          else
            addr = (size_t)2 * 2097152 + (size_t)bh * 32768 + (size_t)d * 1024 + nn;
          base[addr] = f2bf(v);
        }
      }
    } else if (CMODE == 4) {
      float* Cp = (float*)Cv;
#pragma unroll
      for (int nt = 0; nt < 4; nt++) {
        int col = n0 + wn + nt * 16 + fr;
#pragma unroll
        for (int r = 0; r < 4; r++)
          Cp[(size_t)(row0 + r) * ldc + col] = acc[mt][nt][r];
      }
    } else {
#pragma unroll
      for (int nt = 0; nt < 4; nt++) {
        int col = n0 + wn + nt * 16 + fr;
        float bv = bias ? bias[col] : 0.f;
        unsigned short* C = (unsigned short*)Cv;
#pragma unroll
        for (int r = 0; r < 4; r++)
          C[(size_t)(row0 + r) * ldc + col] = f2bf(acc[mt][nt][r] + bv);
      }
    }
  }
}

// ---------------------------------------------------------------------------
// MFMA flash attention — barrier-free, rolled 8x2 pipelined loop (round 7).
__global__ __launch_bounds__(512) void attn_mfma_kernel(
    const unsigned short* __restrict__ Qb, const unsigned short* __restrict__ Kb,
    const unsigned short* __restrict__ Vtb,
    const float* __restrict__ tableT,
    unsigned short* __restrict__ out) {
  __shared__ float th[3972];                 // per-head RPE table column
  __shared__ unsigned short Ps[2][8][1088];  // [half][wave][16*68] P scratch

  int tid = threadIdx.x;
  int lane = tid & 63, w = tid >> 6;
  int n = lane & 15, g = lane >> 4;
  int blk = blockIdx.x;
  int h = blk & 7, b = (blk >> 3) & 7, qt = blk >> 6;
  int bh = b * 8 + h;
  int q0 = qt * 128;

  const unsigned short* Qg = Qb + ((size_t)bh * 1024 + q0) * 32;
  const unsigned short* Kg = Kb + (size_t)bh * 1024 * 32;
  const unsigned short* Vg = Vtb + (size_t)bh * 32 * 1024;
  const float* tg = tableT + (size_t)h * 4096;

  for (int i = tid; i < 3969; i += 512) th[i] = tg[i];
  bf16x8 qf = *(const bf16x8*)(Qg + (size_t)(w * 16 + n) * 32 + g * 8);
  __syncthreads();  // table ready — the only barrier

  f32x4 oacc[2];
  oacc[0] = (f32x4){0.f, 0.f, 0.f, 0.f};
  oacc[1] = (f32x4){0.f, 0.f, 0.f, 0.f};
  float m_run = -1e30f, l_run = 0.f;  // l_run g-partial, reduced at end

  int q = q0 + w * 16 + n;
  int tbase = (q >> 5) * 63 + (q & 31) + 1984;  // + (31*63+31)

  unsigned short* PwA = &Ps[0][w][0];
  unsigned short* PwB = &Ps[1][w][0];

  bf16x8 kfA[4], kfB[4];
#pragma unroll
  for (int mt = 0; mt < 4; mt++)
    kfA[mt] = *(const bf16x8*)(Kg + (size_t)(mt * 16 + n) * 32 + g * 8);

  auto half_step = [&](const bf16x8 (&kf)[4], int k0, unsigned short* Pw) {
    bf16x8 vf[4];
#pragma unroll
    for (int i = 0; i < 4; i++)
      vf[i] = *(const bf16x8*)(Vg + (size_t)((i & 1) * 16 + n) * 1024 + k0 +
                               (i >> 1) * 32 + g * 8);

    f32x4 s[4];
    __builtin_amdgcn_s_setprio(1);
#pragma unroll
    for (int mt = 0; mt < 4; mt++)
      s[mt] = __builtin_amdgcn_mfma_f32_16x16x32_bf16(
          kf[mt], qf, (f32x4){0.f, 0.f, 0.f, 0.f}, 0, 0, 0);
    __builtin_amdgcn_s_setprio(0);

#pragma unroll
    for (int mt = 0; mt < 4; mt++) {
      int kb = k0 + mt * 16 + g * 4;
      int ib = tbase - (kb >> 5) * 63 - (kb & 31);
      s[mt][0] += th[ib];
      s[mt][1] += th[ib - 1];
      s[mt][2] += th[ib - 2];
      s[mt][3] += th[ib - 3];
    }

    float mx = -1e30f;
#pragma unroll
    for (int mt = 0; mt < 4; mt++)
#pragma unroll
      for (int r = 0; r < 4; r++) mx = fmaxf(mx, s[mt][r]);
    mx = fmaxf(mx, __shfl_xor(mx, 16, 64));
    mx = fmaxf(mx, __shfl_xor(mx, 32, 64));
    float m_new = fmaxf(m_run, mx);
    float alpha = __expf(m_run - m_new);
    m_run = m_new;

    float ls = 0.f;
#pragma unroll
    for (int mt = 0; mt < 4; mt++) {
#pragma unroll
      for (int r = 0; r < 4; r++) {
        float p = __expf(s[mt][r] - m_new);
        s[mt][r] = p;
        ls += p;
      }
      u16x4 pk = {f2bf(s[mt][0]), f2bf(s[mt][1]), f2bf(s[mt][2]),
                  f2bf(s[mt][3])};
      *(u16x4*)(Pw + n * 68 + mt * 16 + g * 4) = pk;
    }
    l_run = l_run * alpha + ls;

#pragma unroll
    for (int dt = 0; dt < 2; dt++)
#pragma unroll
      for (int r = 0; r < 4; r++) oacc[dt][r] *= alpha;
    __builtin_amdgcn_s_setprio(1);
#pragma unroll
    for (int kt = 0; kt < 2; kt++) {
      bf16x8 pf = *(const bf16x8*)(Pw + n * 68 + kt * 32 + g * 8);
      oacc[0] = __builtin_amdgcn_mfma_f32_16x16x32_bf16(vf[kt * 2 + 0], pf,
                                                        oacc[0], 0, 0, 0);
      oacc[1] = __builtin_amdgcn_mfma_f32_16x16x32_bf16(vf[kt * 2 + 1], pf,
                                                        oacc[1], 0, 0, 0);
    }
    __builtin_amdgcn_s_setprio(0);
  };

  for (int tt = 0; tt < 8; tt++) {
    int k0 = tt * 128;
#pragma unroll
    for (int mt = 0; mt < 4; mt++)
      kfB[mt] = *(const bf16x8*)(Kg + (size_t)(k0 + 64 + mt * 16 + n) * 32 +
                                 g * 8);
    half_step(kfA, k0, PwA);
    if (tt < 7) {
#pragma unroll
      for (int mt = 0; mt < 4; mt++)
        kfA[mt] = *(const bf16x8*)(Kg + (size_t)(k0 + 128 + mt * 16 + n) * 32 +
                                   g * 8);
    }
    half_step(kfB, k0 + 64, PwB);
  }

  float l = l_run;
  l += __shfl_xor(l, 16, 64);
  l += __shfl_xor(l, 32, 64);
  float invl = 1.f / l;
  unsigned short* ob = out + ((size_t)(b * 1024 + q) * 256) + h * 32;
#pragma unroll
  for (int dt = 0; dt < 2; dt++) {
    u16x4 o4 = {f2bf(oacc[dt][0] * invl), f2bf(oacc[dt][1] * invl),
                f2bf(oacc[dt][2] * invl), f2bf(oacc[dt][3] * invl)};
    *(u16x4*)(ob + dt * 16 + g * 4) = o4;
  }
}

// ---------------------------------------------------------------------------
extern "C" void kernel_launch(void* const* d_in, const int* in_sizes, int n_in,
                              void* d_out, int out_size, void* d_ws, size_t ws_size,
                              hipStream_t stream) {
  const float* x         = (const float*)d_in[0];
  const float* w_embed   = (const float*)d_in[1];
  const float* b_embed   = (const float*)d_in[2];
  const float* cpb_w1    = (const float*)d_in[3];
  const float* cpb_b1    = (const float*)d_in[4];
  const float* cpb_w2    = (const float*)d_in[5];
  const float* w_qkv     = (const float*)d_in[6];
  const float* b_qkv     = (const float*)d_in[7];
  const float* w_proj    = (const float*)d_in[8];
  const float* b_proj    = (const float*)d_in[9];
  const float* w_unembed = (const float*)d_in[10];
  const float* b_unembed = (const float*)d_in[11];
  float* out = (float*)d_out;

  // workspace layout
  char* w = (char*)d_ws;
  float*          ProjP = (float*)w;          w += (size_t)8388608 * 4;      // 32 MB (proj partials)
  unsigned short* tok   = (unsigned short*)w; w += (size_t)8192 * 256 * 2;   //  4 MB
  unsigned short* wE    = (unsigned short*)w; w += (size_t)1048576 * 2;      //  2 MB
  unsigned short* wQ    = (unsigned short*)w; w += (size_t)196608 * 2;       // 384 KB
  unsigned short* wP    = (unsigned short*)w; w += (size_t)65536 * 2;        // 128 KB
  unsigned short* wUt   = (unsigned short*)w; w += (size_t)1048576 * 2;      //  2 MB
  float*          tableT= (float*)w;          w += (size_t)32768 * 4;        // 128 KB
  float*          PART  = (float*)w;          w += (size_t)8388608 * 4;      // 32 MB

  // live-range aliases inside PART (embed partials dead once reduced):
  unsigned short* qkvB  = (unsigned short*)PART;                     // 12 MB
  unsigned short* attno = (unsigned short*)((char*)PART + 12582912); //  4 MB
  unsigned short* z2    = (unsigned short*)((char*)PART + 16777216); //  4 MB
  unsigned short* Qb  = qkvB;
  unsigned short* Kb  = qkvB + 2097152;
  unsigned short* Vtb = qkvB + 2 * 2097152;

  // ---- prep (weights, RPE table) ----
  cvt_bf16_kernel<<<512, 256, 0, stream>>>(w_embed, wE, 131072);
  cvt_bf16_kernel<<<96, 256, 0, stream>>>(w_qkv, wQ, 24576);
  cvt_bf16_kernel<<<32, 256, 0, stream>>>(w_proj, wP, 8192);
  transpose_cvt_kernel<<<dim3(128, 8), 256, 0, stream>>>(w_unembed, wUt);
  rpe_table_kernel<<<16, 256, 0, stream>>>(cpb_w1, cpb_b1, cpb_w2, tableT);

  // ---- embed: barrier-free fused-im2col split-K x4 -> reduce -> tok ----
  gemm_embed_kernel<<<512, 256, 0, stream>>>(x, wE, PART);
  splitk_reduce_kernel<<<1024, 256, 0, stream>>>(PART, b_embed, tok);

  // ---- qkv + fused split/scale/transpose into Qb/Kb/Vtb ----
  gemm_mfma_kernel<3><<<dim3(6, 64), 256, 0, stream>>>(
      tok, wQ, b_qkv, qkvB, 8192, 768, 256, 256, 256, 0);

  // ---- attention (barrier-free, rolled 8x2) ----
  attn_mfma_kernel<<<512, 512, 0, stream>>>(Qb, Kb, Vtb, tableT, attno);

  // ---- proj: split-K x4 -> reduce -> z2 ----
  gemm_mfma_kernel<4><<<dim3(2, 64, 4), 256, 0, stream>>>(
      attno, wP, nullptr, ProjP, 8192, 256, 64, 256, 256, 256);
  splitk_reduce_kernel<<<1024, 256, 0, stream>>>(ProjP, b_proj, z2);

  // ---- unembed + fused col2im ----
  gemm_mfma_kernel<2><<<dim3(32, 64), 256, 0, stream>>>(
      z2, wUt, b_unembed, out, 8192, 4096, 256, 256, 256, 0);
}